// Round 15
// baseline (135.952 us; speedup 1.0000x reference)
//
#include <hip/hip_runtime.h>

typedef __attribute__((ext_vector_type(4)))  float  f32x4;
typedef __attribute__((ext_vector_type(16))) float  f32x16;
typedef __attribute__((ext_vector_type(8)))  short  s16x8;

#define DEVI __device__ __forceinline__

// ---------------- constants ----------------
constexpr int Bb   = 2;
constexpr int Nn   = 2048;
constexpr int Hh   = 16;
constexpr int DHc  = 64;
constexpr int CTXN = 256;
constexpr int Jv   = Nn + 1 + CTXN;   // 2305 valid kv tokens
constexpr int JP   = 2432;            // padded to 38*64 (2 teams x 19 tiles)
constexpr int QKVN = Hh*DHc + 2*DHc;  // 1152

// ---------------- helpers ----------------
DEVI unsigned short f2bf(float f) {
    union { float f; unsigned u; } v; v.f = f;
    unsigned r = v.u + 0x7fffu + ((v.u >> 16) & 1u);
    return (unsigned short)(r >> 16);
}
DEVI float bf2f(unsigned short h) {
    union { unsigned u; float f; } v; v.u = ((unsigned)h) << 16;
    return v.f;
}
DEVI unsigned cvt_pk_bf(float lo, float hi) {   // dst.lo=bf16(lo), dst.hi=bf16(hi)
    unsigned r;
    asm("v_cvt_pk_bf16_f32 %0, %1, %2" : "=v"(r) : "v"(lo), "v"(hi));
    return r;
}
DEVI float exp2v(float x) {                      // v_exp_f32 = 2^x
    float r;
    asm("v_exp_f32 %0, %1" : "=v"(r) : "v"(x));
    return r;
}
// async global->LDS, 16B per lane; LDS dest = uniform base + lane*16 (linear)
DEVI void gl_lds16(const void* g, void* l) {
    __builtin_amdgcn_global_load_lds(
        (__attribute__((address_space(1))) void*)g,
        (__attribute__((address_space(3))) void*)l,
        16, 0, 0);
}

// -------- fused: weight transposes (0..2303) + input LNs (2304..6911) + kv null/pad (6912) --
__global__ __launch_bounds__(256) void k_pre(const float* __restrict__ Wq,
                                             const float* __restrict__ Wkv,
                                             const float* __restrict__ Wc,
                                             const float* __restrict__ Wout,
                                             const float* __restrict__ x,
                                             const float* __restrict__ ctx,
                                             const float* __restrict__ g1,
                                             const float* __restrict__ cg,
                                             const float* __restrict__ cb,
                                             const float* __restrict__ nkv,
                                             unsigned short* __restrict__ WqkvT,
                                             unsigned short* __restrict__ WcT,
                                             unsigned short* __restrict__ WoutT,
                                             unsigned short* __restrict__ h,
                                             unsigned short* __restrict__ ch,
                                             unsigned short* __restrict__ Kb,
                                             unsigned short* __restrict__ Vt,
                                             float qscale) {
    int bxg = blockIdx.x;
    if (bxg < 2304) {
        __shared__ float tile[32][33];
        int bx = bxg % 72, by = bxg / 72;
        const float* in; unsigned short* out; int C; float scale; int cb_;
        if (bx < 32)      { in = Wq;   out = WqkvT;               C = 1024; scale = qscale; cb_ = bx; }
        else if (bx < 36) { in = Wkv;  out = WqkvT + 1024 * 1024; C = 128;  scale = 1.0f;  cb_ = bx - 32; }
        else if (bx < 40) { in = Wc;   out = WcT;                 C = 128;  scale = 1.0f;  cb_ = bx - 36; }
        else              { in = Wout; out = WoutT;               C = 1024; scale = 1.0f;  cb_ = bx - 40; }
        int tx = threadIdx.x & 31, ty = threadIdx.x >> 5;   // 32 x 8
        int r0 = by * 32, c0 = cb_ * 32;
#pragma unroll
        for (int i = 0; i < 32; i += 8)
            tile[ty + i][tx] = in[(size_t)(r0 + ty + i) * C + c0 + tx];
        __syncthreads();
#pragma unroll
        for (int i = 0; i < 32; i += 8)
            out[(size_t)(c0 + ty + i) * 1024 + r0 + tx] = f2bf(tile[tx][ty + i] * scale);
    } else if (bxg < 6912) {
        int row = bxg - 2304, tid = threadIdx.x;
        bool isx = row < 4096;
        const float* rp = isx ? x + (size_t)row * 1024 : ctx + (size_t)(row - 4096) * 1024;
        const float* g  = isx ? g1 : cg;
        float eps = isx ? 1e-5f : 1e-6f;
        unsigned short* o = isx ? h + (size_t)row * 1024 : ch + (size_t)(row - 4096) * 1024;

        f32x4 v = *(const f32x4*)(rp + tid * 4);
        float s = v.x + v.y + v.z + v.w;
        float q = v.x * v.x + v.y * v.y + v.z * v.z + v.w * v.w;
#pragma unroll
        for (int m = 32; m; m >>= 1) { s += __shfl_down(s, m, 64); q += __shfl_down(q, m, 64); }
        __shared__ float ss[4], sq[4];
        int wid = tid >> 6, lane = tid & 63;
        if (lane == 0) { ss[wid] = s; sq[wid] = q; }
        __syncthreads();
        s = ss[0] + ss[1] + ss[2] + ss[3];
        q = sq[0] + sq[1] + sq[2] + sq[3];
        float mean = s * (1.0f / 1024.0f);
        float var  = q * (1.0f / 1024.0f) - mean * mean;
        float rstd = rsqrtf(var + eps);
        f32x4 gg = *(const f32x4*)(g + tid * 4);
        f32x4 r;
#pragma unroll
        for (int e = 0; e < 4; e++) r[e] = (v[e] - mean) * rstd * gg[e];
        if (!isx) {
            f32x4 bb = *(const f32x4*)(cb + tid * 4);
#pragma unroll
            for (int e = 0; e < 4; e++) r[e] += bb[e];
        }
        uint2 ov = make_uint2(cvt_pk_bf(r[0], r[1]), cvt_pk_bf(r[2], r[3]));
        *(uint2*)(o + tid * 4) = ov;
    } else {
        // kv tail: null token j=Nn (both batches) + zero padding j in [Jv, JP)
        int t = threadIdx.x;
        if (t < 128) {
            int b = t >> 6, d = t & 63;
            Kb[((size_t)b * JP + Nn) * 64 + d] = f2bf(nkv[d]);
            Vt[((size_t)b * 64 + d) * JP + Nn] = f2bf(nkv[64 + d]);
        }
        for (int idx = t; idx < 2 * (JP - Jv) * 64; idx += 256) {
            int b = idx / ((JP - Jv) * 64);
            int rem = idx % ((JP - Jv) * 64);
            int j = Jv + rem / 64;
            int d = rem % 64;
            Kb[((size_t)b * JP + j) * 64 + d] = 0;
            Vt[((size_t)b * 64 + d) * JP + j] = 0;
        }
    }
}

// ---------------- final LayerNorm (bf16 in, f32 out) ----------------
__global__ __launch_bounds__(256) void k_ln_out(const unsigned short* __restrict__ in,
                                                const float* __restrict__ g,
                                                float* __restrict__ out) {
    int row = blockIdx.x, tid = threadIdx.x;
    const unsigned short* rp = in + (size_t)row * 1024;
    uint2 raw = *(const uint2*)(rp + tid * 4);
    f32x4 v;
    v.x = bf2f((unsigned short)(raw.x & 0xffff));
    v.y = bf2f((unsigned short)(raw.x >> 16));
    v.z = bf2f((unsigned short)(raw.y & 0xffff));
    v.w = bf2f((unsigned short)(raw.y >> 16));
    float s = v.x + v.y + v.z + v.w;
    float q = v.x * v.x + v.y * v.y + v.z * v.z + v.w * v.w;
#pragma unroll
    for (int m = 32; m; m >>= 1) { s += __shfl_down(s, m, 64); q += __shfl_down(q, m, 64); }
    __shared__ float ss[4], sq[4];
    int wid = tid >> 6, lane = tid & 63;
    if (lane == 0) { ss[wid] = s; sq[wid] = q; }
    __syncthreads();
    s = ss[0] + ss[1] + ss[2] + ss[3];
    q = sq[0] + sq[1] + sq[2] + sq[3];
    float mean = s * (1.0f / 1024.0f);
    float var  = q * (1.0f / 1024.0f) - mean * mean;
    float rstd = rsqrtf(var + 1e-5f);
    f32x4 gg = *(const f32x4*)(g + tid * 4);
    f32x4 r;
#pragma unroll
    for (int e = 0; e < 4; e++) r[e] = (v[e] - mean) * rstd * gg[e];
    *(f32x4*)(out + (size_t)row * 1024 + tid * 4) = r;
}

// ------- GEMM core: 128x128 tile + 3-buffer ring + counted vmcnt (T4 at 1 block/CU) -------
// 4 waves (2x2), wave = 64x64 (4x4 frags): 32 MFMA per K-step vs 16 ds_read_b128.
// Per wave per stage: 8 gl_lds. Ring keeps 2 stages in flight -> vmcnt(16) not vmcnt(0).
// MODE 0: bf16 store to C. MODE 1: qkv (bn<8 normal; bn==8 -> split to Kb/Vt).
// MODE 2: ckv (bias + split to Kb/Vt at j = 2049+cn).
template<int MODE>
DEVI void gemm128(unsigned short* SAb, unsigned short* SBb,
                  const unsigned short* __restrict__ A,
                  const unsigned short* __restrict__ BT,
                  unsigned short* __restrict__ C,
                  int M, int N, int K, int bn, int bm,
                  unsigned short* __restrict__ Kb,
                  unsigned short* __restrict__ Vt,
                  const float* __restrict__ bias) {
    int tid = threadIdx.x;
    int wid = tid >> 6, lane = tid & 63;
    int wm = wid >> 1, wn = wid & 1;
    int lr = lane & 15, lg = lane >> 4;
    int r8 = lane >> 3;
    int sl = (lane & 7) ^ r8;           // pre-swizzled source slot (both-sides XOR, rule #21)

    const unsigned short* Ag = A  + (size_t)(bm * 128 + wid * 32 + r8) * K + sl * 8;
    const unsigned short* Bg = BT + (size_t)(bn * 128 + wid * 32 + r8) * K + sl * 8;

    auto stage = [&](int buf, int s) {
        int k0 = s << 6;
        unsigned short* SA = SAb + buf * (128 * 64);
        unsigned short* SB = SBb + buf * (128 * 64);
#pragma unroll
        for (int i = 0; i < 4; i++) {
            gl_lds16(Ag + (size_t)i * 8 * K + k0, SA + wid * 2048 + i * 512);
            gl_lds16(Bg + (size_t)i * 8 * K + k0, SB + wid * 2048 + i * 512);
        }
    };

    f32x4 acc[4][4] = {};
    int nk = K >> 6;
    stage(0, 0);
    stage(1, 1);
    int b0 = 0;
#pragma unroll 1
    for (int s = 0; s < nk; ++s) {
        int b2 = b0 + 2; if (b2 >= 3) b2 -= 3;
        if (s + 2 < nk) {
            stage(b2, s + 2);
            asm volatile("s_waitcnt vmcnt(16)" ::: "memory");
        } else if (s + 1 < nk) {
            asm volatile("s_waitcnt vmcnt(8)" ::: "memory");
        } else {
            asm volatile("s_waitcnt vmcnt(0)" ::: "memory");
        }
        __builtin_amdgcn_s_barrier();            // all waves' stage(s) landed
        __builtin_amdgcn_sched_barrier(0);
        const unsigned short* Al = SAb + b0 * (128 * 64);
        const unsigned short* Bl = SBb + b0 * (128 * 64);
#pragma unroll
        for (int kk = 0; kk < 2; kk++) {
            int co = ((kk * 4 + lg) ^ (lr & 7)) * 8;
            s16x8 af[4], bf[4];
#pragma unroll
            for (int mi = 0; mi < 4; mi++)
                af[mi] = *(const s16x8*)&Al[(wm * 64 + mi * 16 + lr) * 64 + co];
#pragma unroll
            for (int ni = 0; ni < 4; ni++)
                bf[ni] = *(const s16x8*)&Bl[(wn * 64 + ni * 16 + lr) * 64 + co];
#pragma unroll
            for (int mi = 0; mi < 4; mi++)
#pragma unroll
                for (int ni = 0; ni < 4; ni++)
                    acc[mi][ni] = __builtin_amdgcn_mfma_f32_16x16x32_bf16(af[mi], bf[ni], acc[mi][ni], 0, 0, 0);
        }
        __builtin_amdgcn_sched_barrier(0);
        __builtin_amdgcn_s_barrier();            // buf b0 free to restage
        b0 = b0 + 1; if (b0 >= 3) b0 = 0;
    }
#pragma unroll
    for (int mi = 0; mi < 4; mi++)
#pragma unroll
        for (int r = 0; r < 4; r++) {
            int row = bm * 128 + wm * 64 + mi * 16 + lg * 4 + r;
#pragma unroll
            for (int ni = 0; ni < 4; ni++) {
                int col = bn * 128 + wn * 64 + ni * 16 + lr;
                float val = acc[mi][ni][r];
                if (MODE == 0) {
                    C[(size_t)row * N + col] = f2bf(val);
                } else if (MODE == 1) {
                    if (bn < 8) {
                        C[(size_t)row * N + col] = f2bf(val);
                    } else {
                        int b = row >> 11, j = row & 2047, c = col - 1024;
                        if (c < 64) Kb[((size_t)b * JP + j) * 64 + c] = f2bf(val);
                        else        Vt[((size_t)b * 64 + (c - 64)) * JP + j] = f2bf(val);
                    }
                } else {
                    int b = row >> 8, j = 2049 + (row & 255);
                    float v2 = val + bias[col];
                    if (col < 64) Kb[((size_t)b * JP + j) * 64 + col] = f2bf(v2);
                    else          Vt[((size_t)b * 64 + (col - 64)) * JP + j] = f2bf(v2);
                }
            }
        }
}

// fused qkv (blocks 0..287: 32x9, kv cols -> Kb/Vt) + ckv (blocks 288..291 -> Kb/Vt w/ bias)
__global__ __launch_bounds__(256) void k_gemm_qkv(const unsigned short* __restrict__ h,
                                                  const unsigned short* __restrict__ WqkvT,
                                                  unsigned short* __restrict__ qkv,
                                                  const unsigned short* __restrict__ ch,
                                                  const unsigned short* __restrict__ WcT,
                                                  unsigned short* __restrict__ Kb,
                                                  unsigned short* __restrict__ Vt,
                                                  const float* __restrict__ bc) {
    __shared__ unsigned short SA[3][128 * 64];
    __shared__ unsigned short SB[3][128 * 64];
    int id = blockIdx.x;
    if (id < 288)
        gemm128<1>(&SA[0][0], &SB[0][0], h, WqkvT, qkv, 4096, 1152, 1024, id % 9, id / 9, Kb, Vt, nullptr);
    else
        gemm128<2>(&SA[0][0], &SB[0][0], ch, WcT, nullptr, 512, 128, 1024, 0, id - 288, Kb, Vt, bc);
}

// out projection -> bf16 into reused h_ buffer (32x8 = 256 blocks)
__global__ __launch_bounds__(256) void k_gemm_out(const unsigned short* __restrict__ aout,
                                                  const unsigned short* __restrict__ WoutT,
                                                  unsigned short* __restrict__ preout) {
    __shared__ unsigned short SA[3][128 * 64];
    __shared__ unsigned short SB[3][128 * 64];
    int id = blockIdx.x;
    gemm128<0>(&SA[0][0], &SB[0][0], aout, WoutT, preout, 4096, 1024, 1024, id % 8, id / 8,
               nullptr, nullptr, nullptr);
}

// ---------------- flash attention: j-split teams, 32x32 MFMA, in-register P ----------------
// grid: b(2) x h(16) x qtile(16).  block = 512 = 8 waves = 2 j-teams x 4 waves.
// No max subtraction (scores bounded; softmax shift-invariant): p = exp2(s) raw.
__global__ __launch_bounds__(512) void k_attn(const unsigned short* __restrict__ qkv,
                                              const unsigned short* __restrict__ Kb,
                                              const unsigned short* __restrict__ Vt,
                                              unsigned short* __restrict__ aout) {
    __shared__ unsigned short KV[2][2][2][64 * 64];  // [team][buf][0=K j-rows|1=V^T d-rows] : 64 KB

    int bid = blockIdx.x;
    int qt = bid & 15, h = (bid >> 4) & 15, b = bid >> 8;
    int tid = threadIdx.x, wid = tid >> 6, lane = tid & 63;
    int tm = wid >> 2, tw = wid & 3;
    int l31 = lane & 31, hi = lane >> 5;
    int n0 = qt * 128 + tw * 32;
    int r8 = lane >> 3;
    int sl = (lane & 7) ^ r8;
    int x7 = l31 & 7;
    int jb = tm * 1216;                              // team j-base (19 tiles of 64)

    // Q B-frags: col q = n0+l31, k(d) = kk*16 + hi*8 + e
    s16x8 qf[4];
#pragma unroll
    for (int kk = 0; kk < 4; kk++)
        qf[kk] = *(const s16x8*)(qkv + (size_t)(b * Nn + n0 + l31) * QKVN + h * 64 + kk * 16 + hi * 8);

    f32x16 O0 = {}, O1 = {};            // O^T: col q=l31; d = df*32 + (r&3)+8*(r>>2)+4*hi
    float Lv = 0.0f;

    const unsigned short* Kg = Kb + ((size_t)b * JP + jb + tw * 16 + r8) * 64 + sl * 8;
    const unsigned short* Vg = Vt + ((size_t)b * 64 + tw * 16 + r8) * JP + jb + sl * 8;

    auto stage = [&](int t, int buf) {
#pragma unroll
        for (int i = 0; i < 2; i++) {
            gl_lds16(Kg + ((size_t)t * 64 + i * 8) * 64, &KV[tm][buf][0][tw * 1024 + i * 512]);
            gl_lds16(Vg + (size_t)i * 8 * JP + t * 64,   &KV[tm][buf][1][tw * 1024 + i * 512]);
        }
    };

    auto build_pf = [&](const f32x16& s, int w) -> s16x8 {
        unsigned c0 = cvt_pk_bf(s[8 * w + 0], s[8 * w + 1]);
        unsigned c1 = cvt_pk_bf(s[8 * w + 2], s[8 * w + 3]);
        unsigned c2 = cvt_pk_bf(s[8 * w + 4], s[8 * w + 5]);
        unsigned c3 = cvt_pk_bf(s[8 * w + 6], s[8 * w + 7]);
        asm("v_permlane32_swap_b32 %0, %1" : "+v"(c0), "+v"(c2));
        asm("v_permlane32_swap_b32 %0, %1" : "+v"(c1), "+v"(c3));
        union { unsigned u[4]; s16x8 v; } pu;
        pu.u[0] = c0; pu.u[1] = c1; pu.u[2] = c2; pu.u[3] = c3;
        return pu.v;
    };

    stage(0, 0);
    asm volatile("s_waitcnt vmcnt(0)" ::: "memory");
    asm volatile("s_barrier" ::: "memory");
    int cur = 0;
#pragma unroll 1
    for (int t = 0; t < 19; ++t) {
        if (t < 18) {
            stage(t + 1, cur ^ 1);                          // 4 loads into other buf
            asm volatile("s_waitcnt vmcnt(4)" ::: "memory"); // my stage(t) landed; t+1 in flight
        } else {
            asm volatile("s_waitcnt vmcnt(0)" ::: "memory");
        }
        asm volatile("s_barrier" ::: "memory");              // all waves' stage(t) landed
        __builtin_amdgcn_sched_barrier(0);
        const unsigned short* Kl = &KV[tm][cur][0][0];
        const unsigned short* Vl = &KV[tm][cur][1][0];
        int j0 = jb + t * 64;

        // S^T = K Q^T : lane = col q; rows j = j0 + jf*32 + (r&3)+8*(r>>2)+4*hi  (log2 units)
        f32x16 s0 = {}, s1 = {};
        __builtin_amdgcn_s_setprio(1);
#pragma unroll
        for (int kk = 0; kk < 4; kk++) {
            int co = ((kk * 2 + hi) ^ x7) * 8;
            s16x8 k0 = *(const s16x8*)&Kl[l31 * 64 + co];
            s16x8 k1 = *(const s16x8*)&Kl[(32 + l31) * 64 + co];
            s0 = __builtin_amdgcn_mfma_f32_32x32x16_bf16(k0, qf[kk], s0, 0, 0, 0);
            s1 = __builtin_amdgcn_mfma_f32_32x32x16_bf16(k1, qf[kk], s1, 0, 0, 0);
        }
        __builtin_amdgcn_s_setprio(0);
        if (j0 + 64 > Jv) {             // mask padded tokens (uniform branch; team1 tail)
#pragma unroll
            for (int r = 0; r < 16; r++) {
                int ja = j0 + (r & 3) + 8 * (r >> 2) + 4 * hi;
                if (ja >= Jv)      s0[r] = -1e30f;
                if (ja + 32 >= Jv) s1[r] = -1e30f;
            }
        }

        // softmax weights: p = exp2(s); masked -> 0
        float sum = 0.0f;
#pragma unroll
        for (int r = 0; r < 16; r++) { s0[r] = exp2v(s0[r]); sum += s0[r]; }
#pragma unroll
        for (int r = 0; r < 16; r++) { s1[r] = exp2v(s1[r]); sum += s1[r]; }
        Lv += sum;

        // O^T += V^T P^T ; P^T frags in-register
        __builtin_amdgcn_s_setprio(1);
#pragma unroll
        for (int ks = 0; ks < 4; ks++) {
            s16x8 pf = (ks < 2) ? build_pf(s0, ks & 1) : build_pf(s1, ks & 1);
            int co = ((ks * 2 + hi) ^ x7) * 8;
            s16x8 v0 = *(const s16x8*)&Vl[l31 * 64 + co];
            s16x8 v1 = *(const s16x8*)&Vl[(32 + l31) * 64 + co];
            O0 = __builtin_amdgcn_mfma_f32_32x32x16_bf16(v0, pf, O0, 0, 0, 0);
            O1 = __builtin_amdgcn_mfma_f32_32x32x16_bf16(v1, pf, O1, 0, 0, 0);
        }
        __builtin_amdgcn_s_setprio(0);
        __builtin_amdgcn_sched_barrier(0);
        asm volatile("s_barrier" ::: "memory");  // all waves done reading buf cur
        cur ^= 1;
    }

    // combine partner-lane L (other 32 j's of same q within team)
    Lv += __shfl_xor(Lv, 32, 64);

    // ------- team merge via LDS (KV dead now): plain adds -------
    float* Ob = (float*)&KV[0][0][0][0];                 // [4][64][33] f32 (+1 pad)
    float* Ml = Ob + 4 * 64 * 33;                        // [4][64] L values
    unsigned short* slabs = (unsigned short*)(Ml + 4 * 64); // team0: 4 x (32q x 72)

    __syncthreads();
    if (tm == 1) {
        float* dst = Ob + ((size_t)tw * 64 + lane) * 33;
#pragma unroll
        for (int r = 0; r < 16; r++) { dst[r] = O0[r]; dst[16 + r] = O1[r]; }
        Ml[tw * 64 + lane] = Lv;
    }
    __syncthreads();
    if (tm == 0) {
        const float* src = Ob + ((size_t)tw * 64 + lane) * 33;
        float rl = 1.0f / (Lv + Ml[tw * 64 + lane]);

        unsigned short* slab = slabs + tw * 2304;        // 32 q x 72
#pragma unroll
        for (int rq = 0; rq < 4; rq++) {
            uint2 w0 = make_uint2(
                cvt_pk_bf((O0[rq * 4 + 0] + src[rq * 4 + 0]) * rl,
                          (O0[rq * 4 + 1] + src[rq * 4 + 1]) * rl),
                cvt_pk_bf((O0[rq * 4 + 2] + src[rq * 4 + 2]) * rl,
                          (O0[rq * 4 + 3] + src[rq * 4 + 3]) * rl));
            *(uint2*)&slab[l31 * 72 + rq * 8 + hi * 4] = w0;
            uint2 w1 = make_uint2(
                cvt_pk_bf((O1[rq * 4 + 0] + src[16 + rq * 4 + 0]) * rl,
                          (O1[rq * 4 + 1] + src[16 + rq * 4 + 1]) * rl),
                cvt_pk_bf((O1[rq * 4 + 2] + src[16 + rq * 4 + 2]) * rl,
                          (O1[rq * 4 + 3] + src[16 + rq * 4 + 3]) * rl));
            *(uint2*)&slab[l31 * 72 + 32 + rq * 8 + hi * 4] = w1;
        }
        // each lane stores 32 shorts
        int q = lane >> 1, half = lane & 1;
        const s16x8* srcq = (const s16x8*)&slab[q * 72 + half * 32];
        s16x8 o0 = srcq[0], o1 = srcq[1], o2 = srcq[2], o3 = srcq[3];
        unsigned short* gdst = aout + (size_t)(b * Nn + n0 + q) * 1024 + h * 64 + half * 32;
        *(s16x8*)gdst = o0;
        *((s16x8*)gdst + 1) = o1;
        *((s16x8*)gdst + 2) = o2;
        *((s16x8*)gdst + 3) = o3;
    }
}

// ---------------- launch ----------------
extern "C" void kernel_launch(void* const* d_in, const int* in_sizes, int n_in,
                              void* d_out, int out_size, void* d_ws, size_t ws_size,
                              hipStream_t stream) {
    const float* x    = (const float*)d_in[0];
    const float* ctx  = (const float*)d_in[1];
    const float* g1   = (const float*)d_in[2];
    const float* Wq   = (const float*)d_in[3];
    const float* Wkv  = (const float*)d_in[4];
    const float* nkv  = (const float*)d_in[5];
    const float* ctxg = (const float*)d_in[6];
    const float* ctxb = (const float*)d_in[7];
    const float* Wc   = (const float*)d_in[8];
    const float* bc   = (const float*)d_in[9];
    const float* Wout = (const float*)d_in[10];
    const float* g2   = (const float*)d_in[11];
    float* out = (float*)d_out;

    char* w = (char*)d_ws;
    unsigned short* h_    = (unsigned short*)w; w += (size_t)4096 * 1024 * 2;
    unsigned short* ch    = (unsigned short*)w; w += (size_t)512 * 1024 * 2;
    unsigned short* WqkvT = (unsigned short*)w; w += (size_t)1152 * 1024 * 2;
    unsigned short* WcT   = (unsigned short*)w; w += (size_t)128 * 1024 * 2;
    unsigned short* WoutT = (unsigned short*)w; w += (size_t)1024 * 1024 * 2;
    unsigned short* qkv   = (unsigned short*)w; w += (size_t)4096 * QKVN * 2;
    unsigned short* Kb    = (unsigned short*)w; w += (size_t)Bb * JP * 64 * 2;
    unsigned short* Vt    = (unsigned short*)w; w += (size_t)Bb * 64 * JP * 2;
    unsigned short* aout  = (unsigned short*)w; w += (size_t)4096 * 1024 * 2;

    // fold softmax scale AND log2(e) into Wq so QK^T lands in exp2 domain
    const float qscale = 0.125f * 1.4426950408889634f;

    // weight transposes + input layernorms + kv null/pad (one fused launch)
    k_pre<<<6913, 256, 0, stream>>>(Wq, Wkv, Wc, Wout, x, ctx, g1, ctxg, ctxb, nkv,
                                    WqkvT, WcT, WoutT, h_, ch, Kb, Vt, qscale);

    // qkv + ckv projections (ring GEMM); kv columns written directly to Kb/Vt
    k_gemm_qkv<<<292, 256, 0, stream>>>(h_, WqkvT, qkv, ch, WcT, Kb, Vt, bc);

    // attention: 512 threads = 2 j-teams x 4 waves; 128 q-rows per block; 512 blocks
    k_attn<<<Bb * Hh * (Nn / 128), 512, 0, stream>>>(qkv, Kb, Vt, aout);

    // output projection (ring GEMM, bf16 into reused h_) + final LN (bf16 in)
    k_gemm_out<<<256, 256, 0, stream>>>(aout, WoutT, h_);
    k_ln_out<<<4096, 256, 0, stream>>>(h_, g2, out);
}

// Round 16
// 113.955 us; speedup vs baseline: 1.1930x; 1.1930x over previous
//
#include <hip/hip_runtime.h>

typedef __attribute__((ext_vector_type(4)))  float  f32x4;
typedef __attribute__((ext_vector_type(16))) float  f32x16;
typedef __attribute__((ext_vector_type(8)))  short  s16x8;

#define DEVI __device__ __forceinline__

// ---------------- constants ----------------
constexpr int Bb   = 2;
constexpr int Nn   = 2048;
constexpr int Hh   = 16;
constexpr int DHc  = 64;
constexpr int CTXN = 256;
constexpr int Jv   = Nn + 1 + CTXN;   // 2305 valid kv tokens
constexpr int JP   = 2432;            // padded to 38*64 (2 teams x 19 tiles)
constexpr int QKVN = Hh*DHc + 2*DHc;  // 1152

// ---------------- helpers ----------------
DEVI unsigned short f2bf(float f) {
    union { float f; unsigned u; } v; v.f = f;
    unsigned r = v.u + 0x7fffu + ((v.u >> 16) & 1u);
    return (unsigned short)(r >> 16);
}
DEVI float bf2f(unsigned short h) {
    union { unsigned u; float f; } v; v.u = ((unsigned)h) << 16;
    return v.f;
}
DEVI unsigned cvt_pk_bf(float lo, float hi) {   // dst.lo=bf16(lo), dst.hi=bf16(hi)
    unsigned r;
    asm("v_cvt_pk_bf16_f32 %0, %1, %2" : "=v"(r) : "v"(lo), "v"(hi));
    return r;
}
DEVI float exp2v(float x) {                      // v_exp_f32 = 2^x
    float r;
    asm("v_exp_f32 %0, %1" : "=v"(r) : "v"(x));
    return r;
}
// async global->LDS, 16B per lane; LDS dest = uniform base + lane*16 (linear)
DEVI void gl_lds16(const void* g, void* l) {
    __builtin_amdgcn_global_load_lds(
        (__attribute__((address_space(1))) void*)g,
        (__attribute__((address_space(3))) void*)l,
        16, 0, 0);
}

// ---------------- fused: weight transposes (blocks 0..2303) + input LNs (2304..6911) -----
__global__ __launch_bounds__(256) void k_pre(const float* __restrict__ Wq,
                                             const float* __restrict__ Wkv,
                                             const float* __restrict__ Wc,
                                             const float* __restrict__ Wout,
                                             const float* __restrict__ x,
                                             const float* __restrict__ ctx,
                                             const float* __restrict__ g1,
                                             const float* __restrict__ cg,
                                             const float* __restrict__ cb,
                                             unsigned short* __restrict__ WqkvT,
                                             unsigned short* __restrict__ WcT,
                                             unsigned short* __restrict__ WoutT,
                                             unsigned short* __restrict__ h,
                                             unsigned short* __restrict__ ch,
                                             float qscale) {
    int bxg = blockIdx.x;
    if (bxg < 2304) {
        __shared__ float tile[32][33];
        int bx = bxg % 72, by = bxg / 72;
        const float* in; unsigned short* out; int C; float scale; int cb_;
        if (bx < 32)      { in = Wq;   out = WqkvT;               C = 1024; scale = qscale; cb_ = bx; }
        else if (bx < 36) { in = Wkv;  out = WqkvT + 1024 * 1024; C = 128;  scale = 1.0f;  cb_ = bx - 32; }
        else if (bx < 40) { in = Wc;   out = WcT;                 C = 128;  scale = 1.0f;  cb_ = bx - 36; }
        else              { in = Wout; out = WoutT;               C = 1024; scale = 1.0f;  cb_ = bx - 40; }
        int tx = threadIdx.x & 31, ty = threadIdx.x >> 5;   // 32 x 8
        int r0 = by * 32, c0 = cb_ * 32;
#pragma unroll
        for (int i = 0; i < 32; i += 8)
            tile[ty + i][tx] = in[(size_t)(r0 + ty + i) * C + c0 + tx];
        __syncthreads();
#pragma unroll
        for (int i = 0; i < 32; i += 8)
            out[(size_t)(c0 + ty + i) * 1024 + r0 + tx] = f2bf(tile[tx][ty + i] * scale);
    } else {
        int row = bxg - 2304, tid = threadIdx.x;
        bool isx = row < 4096;
        const float* rp = isx ? x + (size_t)row * 1024 : ctx + (size_t)(row - 4096) * 1024;
        const float* g  = isx ? g1 : cg;
        float eps = isx ? 1e-5f : 1e-6f;
        unsigned short* o = isx ? h + (size_t)row * 1024 : ch + (size_t)(row - 4096) * 1024;

        f32x4 v = *(const f32x4*)(rp + tid * 4);
        float s = v.x + v.y + v.z + v.w;
        float q = v.x * v.x + v.y * v.y + v.z * v.z + v.w * v.w;
#pragma unroll
        for (int m = 32; m; m >>= 1) { s += __shfl_down(s, m, 64); q += __shfl_down(q, m, 64); }
        __shared__ float ss[4], sq[4];
        int wid = tid >> 6, lane = tid & 63;
        if (lane == 0) { ss[wid] = s; sq[wid] = q; }
        __syncthreads();
        s = ss[0] + ss[1] + ss[2] + ss[3];
        q = sq[0] + sq[1] + sq[2] + sq[3];
        float mean = s * (1.0f / 1024.0f);
        float var  = q * (1.0f / 1024.0f) - mean * mean;
        float rstd = rsqrtf(var + eps);
        f32x4 gg = *(const f32x4*)(g + tid * 4);
        f32x4 r;
#pragma unroll
        for (int e = 0; e < 4; e++) r[e] = (v[e] - mean) * rstd * gg[e];
        if (!isx) {
            f32x4 bb = *(const f32x4*)(cb + tid * 4);
#pragma unroll
            for (int e = 0; e < 4; e++) r[e] += bb[e];
        }
        uint2 ov = make_uint2(cvt_pk_bf(r[0], r[1]), cvt_pk_bf(r[2], r[3]));
        *(uint2*)(o + tid * 4) = ov;
    }
}

// ---------------- final LayerNorm (bf16 in, f32 out) ----------------
__global__ __launch_bounds__(256) void k_ln_out(const unsigned short* __restrict__ in,
                                                const float* __restrict__ g,
                                                float* __restrict__ out) {
    int row = blockIdx.x, tid = threadIdx.x;
    const unsigned short* rp = in + (size_t)row * 1024;
    uint2 raw = *(const uint2*)(rp + tid * 4);
    f32x4 v;
    v.x = bf2f((unsigned short)(raw.x & 0xffff));
    v.y = bf2f((unsigned short)(raw.x >> 16));
    v.z = bf2f((unsigned short)(raw.y & 0xffff));
    v.w = bf2f((unsigned short)(raw.y >> 16));
    float s = v.x + v.y + v.z + v.w;
    float q = v.x * v.x + v.y * v.y + v.z * v.z + v.w * v.w;
#pragma unroll
    for (int m = 32; m; m >>= 1) { s += __shfl_down(s, m, 64); q += __shfl_down(q, m, 64); }
    __shared__ float ss[4], sq[4];
    int wid = tid >> 6, lane = tid & 63;
    if (lane == 0) { ss[wid] = s; sq[wid] = q; }
    __syncthreads();
    s = ss[0] + ss[1] + ss[2] + ss[3];
    q = sq[0] + sq[1] + sq[2] + sq[3];
    float mean = s * (1.0f / 1024.0f);
    float var  = q * (1.0f / 1024.0f) - mean * mean;
    float rstd = rsqrtf(var + 1e-5f);
    f32x4 gg = *(const f32x4*)(g + tid * 4);
    f32x4 r;
#pragma unroll
    for (int e = 0; e < 4; e++) r[e] = (v[e] - mean) * rstd * gg[e];
    *(f32x4*)(out + (size_t)row * 1024 + tid * 4) = r;
}

// ---------------- GEMM core: m97-style 128x128 tile, BK=64, single-buffered -------------
// 4 waves (2x2), wave = 64x64 (4x4 frags): 32 MFMA vs 16 ds_read_b128 per K-step.
// 32 KB LDS -> ~4 blocks/CU resident; inter-block overlap hides the barrier drain.
template<int OUT_BF16>
DEVI void gemm128(unsigned short* Al, unsigned short* Bl,
                  const unsigned short* __restrict__ A,
                  const unsigned short* __restrict__ BT,
                  void* __restrict__ C,
                  int M, int N, int K, int bn, int bm) {
    int tid = threadIdx.x;
    int wid = tid >> 6, lane = tid & 63;
    int wm = wid >> 1, wn = wid & 1;
    int lr = lane & 15, lg = lane >> 4;
    int r8 = lane >> 3;
    int sl = (lane & 7) ^ r8;           // pre-swizzled source slot (both-sides XOR, rule #21)

    const unsigned short* Ag = A  + (size_t)(bm * 128 + wid * 32 + r8) * K + sl * 8;
    const unsigned short* Bg = BT + (size_t)(bn * 128 + wid * 32 + r8) * K + sl * 8;

    f32x4 acc[4][4] = {};
    int nk = K >> 6;
#pragma unroll 1
    for (int s = 0; s < nk; ++s) {
        int k0 = s << 6;
        __syncthreads();                 // prev-iter LDS reads done
#pragma unroll
        for (int i = 0; i < 4; i++) {
            gl_lds16(Ag + (size_t)i * 8 * K + k0, Al + wid * 2048 + i * 512);
            gl_lds16(Bg + (size_t)i * 8 * K + k0, Bl + wid * 2048 + i * 512);
        }
        __syncthreads();                 // drains vmcnt; staged data visible
#pragma unroll
        for (int kk = 0; kk < 2; kk++) {
            int co = ((kk * 4 + lg) ^ (lr & 7)) * 8;
            s16x8 af[4], bf[4];
#pragma unroll
            for (int mi = 0; mi < 4; mi++)
                af[mi] = *(const s16x8*)&Al[(wm * 64 + mi * 16 + lr) * 64 + co];
#pragma unroll
            for (int ni = 0; ni < 4; ni++)
                bf[ni] = *(const s16x8*)&Bl[(wn * 64 + ni * 16 + lr) * 64 + co];
#pragma unroll
            for (int mi = 0; mi < 4; mi++)
#pragma unroll
                for (int ni = 0; ni < 4; ni++)
                    acc[mi][ni] = __builtin_amdgcn_mfma_f32_16x16x32_bf16(af[mi], bf[ni], acc[mi][ni], 0, 0, 0);
        }
    }
#pragma unroll
    for (int mi = 0; mi < 4; mi++)
#pragma unroll
        for (int r = 0; r < 4; r++) {
            int row = bm * 128 + wm * 64 + mi * 16 + lg * 4 + r;
#pragma unroll
            for (int ni = 0; ni < 4; ni++) {
                int col = bn * 128 + wn * 64 + ni * 16 + lr;
                float val = acc[mi][ni][r];
                if (OUT_BF16)
                    ((unsigned short*)C)[(size_t)row * N + col] = f2bf(val);
                else
                    ((float*)C)[(size_t)row * N + col] = val;
            }
        }
}

// fused qkv (blocks 0..287: 32x9) + ckv (blocks 288..291: 4x1) projection
__global__ __launch_bounds__(256) void k_gemm_qkv(const unsigned short* __restrict__ h,
                                                  const unsigned short* __restrict__ WqkvT,
                                                  unsigned short* __restrict__ qkv,
                                                  const unsigned short* __restrict__ ch,
                                                  const unsigned short* __restrict__ WcT,
                                                  unsigned short* __restrict__ ckv) {
    __shared__ unsigned short SA[128 * 64];
    __shared__ unsigned short SB[128 * 64];
    int id = blockIdx.x;
    if (id < 288)
        gemm128<1>(SA, SB, h, WqkvT, qkv, 4096, 1152, 1024, id % 9, id / 9);
    else
        gemm128<1>(SA, SB, ch, WcT, ckv, 512, 128, 1024, 0, id - 288);
}

// out projection -> bf16 into reused h_ buffer (32x8 = 256 blocks, all resident)
__global__ __launch_bounds__(256) void k_gemm_out(const unsigned short* __restrict__ aout,
                                                  const unsigned short* __restrict__ WoutT,
                                                  unsigned short* __restrict__ preout) {
    __shared__ unsigned short SA[128 * 64];
    __shared__ unsigned short SB[128 * 64];
    int id = blockIdx.x;
    gemm128<1>(SA, SB, aout, WoutT, preout, 4096, 1024, 1024, id % 8, id / 8);
}

// ---------------- assemble K (row-major) and V^T via LDS transpose, coalesced ------------
// grid: Bb * 38 j-tiles of 64. Vectorized loads; Kb written coalesced; V staged in LDS
// [64][66] (2-way-free gather) and written to Vt in 16B runs.
__global__ __launch_bounds__(256) void k_assemble_kv(const unsigned short* __restrict__ qkv,
                                                     const unsigned short* __restrict__ ckv,
                                                     const float* __restrict__ nkv,
                                                     const float* __restrict__ bc,
                                                     unsigned short* __restrict__ Kb,
                                                     unsigned short* __restrict__ Vt) {
    __shared__ unsigned short Vl[64][66];
    int bid = blockIdx.x;
    int b = bid / 38, jt = bid % 38;
    int j0 = jt * 64;
    int tid = threadIdx.x;
    int jl = tid >> 2, qu = tid & 3;     // 64 rows x 4 quarters (16 shorts each)
    int j = j0 + jl;

    unsigned short kbuf[16], vbuf[16];
    if (j < Nn) {
        const unsigned short* r = qkv + (size_t)(b * Nn + j) * QKVN + Hh * DHc;
        *(s16x8*)&kbuf[0] = *(const s16x8*)(r + qu * 16);
        *(s16x8*)&kbuf[8] = *(const s16x8*)(r + qu * 16 + 8);
        *(s16x8*)&vbuf[0] = *(const s16x8*)(r + 64 + qu * 16);
        *(s16x8*)&vbuf[8] = *(const s16x8*)(r + 64 + qu * 16 + 8);
    } else if (j == Nn) {
#pragma unroll
        for (int i = 0; i < 16; i++) {
            kbuf[i] = f2bf(nkv[qu * 16 + i]);
            vbuf[i] = f2bf(nkv[64 + qu * 16 + i]);
        }
    } else if (j < Jv) {
        const unsigned short* r = ckv + (size_t)(b * CTXN + (j - Nn - 1)) * 128;
#pragma unroll
        for (int i = 0; i < 16; i++) {
            kbuf[i] = f2bf(bf2f(r[qu * 16 + i]) + bc[qu * 16 + i]);
            vbuf[i] = f2bf(bf2f(r[64 + qu * 16 + i]) + bc[64 + qu * 16 + i]);
        }
    } else {
#pragma unroll
        for (int i = 0; i < 16; i++) { kbuf[i] = 0; vbuf[i] = 0; }
    }
    // K: direct coalesced store
    *(s16x8*)(Kb + ((size_t)b * JP + j) * 64 + qu * 16)     = *(s16x8*)&kbuf[0];
    *(s16x8*)(Kb + ((size_t)b * JP + j) * 64 + qu * 16 + 8) = *(s16x8*)&kbuf[8];
    // V: stage row-major into LDS
#pragma unroll
    for (int i = 0; i < 16; i++) Vl[jl][qu * 16 + i] = vbuf[i];
    __syncthreads();
    // transpose out: thread -> (d = it*32 + tid>>3, 16B chunk pt = tid&7 of the 64-j row)
#pragma unroll
    for (int it = 0; it < 2; it++) {
        int d = it * 32 + (tid >> 3), pt = tid & 7;
        unsigned short ob[8];
#pragma unroll
        for (int i = 0; i < 8; i++) ob[i] = Vl[pt * 8 + i][d];
        *(s16x8*)(Vt + ((size_t)b * 64 + d) * JP + j0 + pt * 8) = *(s16x8*)&ob[0];
    }
}

// ---------------- flash attention: j-split teams, 32x32 MFMA, in-register P ----------------
// grid: b(2) x h(16) x qtile(16).  block = 512 = 8 waves = 2 j-teams x 4 waves.
// No max subtraction (scores bounded; softmax shift-invariant): p = exp2(s) raw.
__global__ __launch_bounds__(512) void k_attn(const unsigned short* __restrict__ qkv,
                                              const unsigned short* __restrict__ Kb,
                                              const unsigned short* __restrict__ Vt,
                                              unsigned short* __restrict__ aout) {
    __shared__ unsigned short KV[2][2][2][64 * 64];  // [team][buf][0=K j-rows|1=V^T d-rows] : 64 KB

    int bid = blockIdx.x;
    int qt = bid & 15, h = (bid >> 4) & 15, b = bid >> 8;
    int tid = threadIdx.x, wid = tid >> 6, lane = tid & 63;
    int tm = wid >> 2, tw = wid & 3;
    int l31 = lane & 31, hi = lane >> 5;
    int n0 = qt * 128 + tw * 32;
    int r8 = lane >> 3;
    int sl = (lane & 7) ^ r8;
    int x7 = l31 & 7;
    int jb = tm * 1216;                              // team j-base (19 tiles of 64)

    // Q B-frags: col q = n0+l31, k(d) = kk*16 + hi*8 + e
    s16x8 qf[4];
#pragma unroll
    for (int kk = 0; kk < 4; kk++)
        qf[kk] = *(const s16x8*)(qkv + (size_t)(b * Nn + n0 + l31) * QKVN + h * 64 + kk * 16 + hi * 8);

    f32x16 O0 = {}, O1 = {};            // O^T: col q=l31; d = df*32 + (r&3)+8*(r>>2)+4*hi
    float Lv = 0.0f;

    const unsigned short* Kg = Kb + ((size_t)b * JP + jb + tw * 16 + r8) * 64 + sl * 8;
    const unsigned short* Vg = Vt + ((size_t)b * 64 + tw * 16 + r8) * JP + jb + sl * 8;

    auto stage = [&](int t, int buf) {
#pragma unroll
        for (int i = 0; i < 2; i++) {
            gl_lds16(Kg + ((size_t)t * 64 + i * 8) * 64, &KV[tm][buf][0][tw * 1024 + i * 512]);
            gl_lds16(Vg + (size_t)i * 8 * JP + t * 64,   &KV[tm][buf][1][tw * 1024 + i * 512]);
        }
    };

    auto build_pf = [&](const f32x16& s, int w) -> s16x8 {
        unsigned c0 = cvt_pk_bf(s[8 * w + 0], s[8 * w + 1]);
        unsigned c1 = cvt_pk_bf(s[8 * w + 2], s[8 * w + 3]);
        unsigned c2 = cvt_pk_bf(s[8 * w + 4], s[8 * w + 5]);
        unsigned c3 = cvt_pk_bf(s[8 * w + 6], s[8 * w + 7]);
        asm("v_permlane32_swap_b32 %0, %1" : "+v"(c0), "+v"(c2));
        asm("v_permlane32_swap_b32 %0, %1" : "+v"(c1), "+v"(c3));
        union { unsigned u[4]; s16x8 v; } pu;
        pu.u[0] = c0; pu.u[1] = c1; pu.u[2] = c2; pu.u[3] = c3;
        return pu.v;
    };

    stage(0, 0);
    asm volatile("s_waitcnt vmcnt(0)" ::: "memory");
    asm volatile("s_barrier" ::: "memory");
    int cur = 0;
#pragma unroll 1
    for (int t = 0; t < 19; ++t) {
        if (t < 18) {
            stage(t + 1, cur ^ 1);                          // 4 loads into other buf
            asm volatile("s_waitcnt vmcnt(4)" ::: "memory"); // my stage(t) landed; t+1 in flight
        } else {
            asm volatile("s_waitcnt vmcnt(0)" ::: "memory");
        }
        asm volatile("s_barrier" ::: "memory");              // all waves' stage(t) landed
        __builtin_amdgcn_sched_barrier(0);
        const unsigned short* Kl = &KV[tm][cur][0][0];
        const unsigned short* Vl = &KV[tm][cur][1][0];
        int j0 = jb + t * 64;

        // S^T = K Q^T : lane = col q; rows j = j0 + jf*32 + (r&3)+8*(r>>2)+4*hi  (log2 units)
        f32x16 s0 = {}, s1 = {};
        __builtin_amdgcn_s_setprio(1);
#pragma unroll
        for (int kk = 0; kk < 4; kk++) {
            int co = ((kk * 2 + hi) ^ x7) * 8;
            s16x8 k0 = *(const s16x8*)&Kl[l31 * 64 + co];
            s16x8 k1 = *(const s16x8*)&Kl[(32 + l31) * 64 + co];
            s0 = __builtin_amdgcn_mfma_f32_32x32x16_bf16(k0, qf[kk], s0, 0, 0, 0);
            s1 = __builtin_amdgcn_mfma_f32_32x32x16_bf16(k1, qf[kk], s1, 0, 0, 0);
        }
        __builtin_amdgcn_s_setprio(0);
        if (j0 + 64 > Jv) {             // mask padded tokens (uniform branch; team1 tail)
#pragma unroll
            for (int r = 0; r < 16; r++) {
                int ja = j0 + (r & 3) + 8 * (r >> 2) + 4 * hi;
                if (ja >= Jv)      s0[r] = -1e30f;
                if (ja + 32 >= Jv) s1[r] = -1e30f;
            }
        }

        // softmax weights: p = exp2(s); masked -> 0
        float sum = 0.0f;
#pragma unroll
        for (int r = 0; r < 16; r++) { s0[r] = exp2v(s0[r]); sum += s0[r]; }
#pragma unroll
        for (int r = 0; r < 16; r++) { s1[r] = exp2v(s1[r]); sum += s1[r]; }
        Lv += sum;

        // O^T += V^T P^T ; P^T frags in-register
        __builtin_amdgcn_s_setprio(1);
#pragma unroll
        for (int ks = 0; ks < 4; ks++) {
            s16x8 pf = (ks < 2) ? build_pf(s0, ks & 1) : build_pf(s1, ks & 1);
            int co = ((ks * 2 + hi) ^ x7) * 8;
            s16x8 v0 = *(const s16x8*)&Vl[l31 * 64 + co];
            s16x8 v1 = *(const s16x8*)&Vl[(32 + l31) * 64 + co];
            O0 = __builtin_amdgcn_mfma_f32_32x32x16_bf16(v0, pf, O0, 0, 0, 0);
            O1 = __builtin_amdgcn_mfma_f32_32x32x16_bf16(v1, pf, O1, 0, 0, 0);
        }
        __builtin_amdgcn_s_setprio(0);
        __builtin_amdgcn_sched_barrier(0);
        asm volatile("s_barrier" ::: "memory");  // all waves done reading buf cur
        cur ^= 1;
    }

    // combine partner-lane L (other 32 j's of same q within team)
    Lv += __shfl_xor(Lv, 32, 64);

    // ------- team merge via LDS (KV dead now): plain adds -------
    float* Ob = (float*)&KV[0][0][0][0];                 // [4][64][33] f32 (+1 pad)
    float* Ml = Ob + 4 * 64 * 33;                        // [4][64] L values
    unsigned short* slabs = (unsigned short*)(Ml + 4 * 64); // team0: 4 x (32q x 72)

    __syncthreads();
    if (tm == 1) {
        float* dst = Ob + ((size_t)tw * 64 + lane) * 33;
#pragma unroll
        for (int r = 0; r < 16; r++) { dst[r] = O0[r]; dst[16 + r] = O1[r]; }
        Ml[tw * 64 + lane] = Lv;
    }
    __syncthreads();
    if (tm == 0) {
        const float* src = Ob + ((size_t)tw * 64 + lane) * 33;
        float rl = 1.0f / (Lv + Ml[tw * 64 + lane]);

        unsigned short* slab = slabs + tw * 2304;        // 32 q x 72
#pragma unroll
        for (int rq = 0; rq < 4; rq++) {
            uint2 w0 = make_uint2(
                cvt_pk_bf((O0[rq * 4 + 0] + src[rq * 4 + 0]) * rl,
                          (O0[rq * 4 + 1] + src[rq * 4 + 1]) * rl),
                cvt_pk_bf((O0[rq * 4 + 2] + src[rq * 4 + 2]) * rl,
                          (O0[rq * 4 + 3] + src[rq * 4 + 3]) * rl));
            *(uint2*)&slab[l31 * 72 + rq * 8 + hi * 4] = w0;
            uint2 w1 = make_uint2(
                cvt_pk_bf((O1[rq * 4 + 0] + src[16 + rq * 4 + 0]) * rl,
                          (O1[rq * 4 + 1] + src[16 + rq * 4 + 1]) * rl),
                cvt_pk_bf((O1[rq * 4 + 2] + src[16 + rq * 4 + 2]) * rl,
                          (O1[rq * 4 + 3] + src[16 + rq * 4 + 3]) * rl));
            *(uint2*)&slab[l31 * 72 + 32 + rq * 8 + hi * 4] = w1;
        }
        // each lane stores 32 shorts
        int q = lane >> 1, half = lane & 1;
        const s16x8* srcq = (const s16x8*)&slab[q * 72 + half * 32];
        s16x8 o0 = srcq[0], o1 = srcq[1], o2 = srcq[2], o3 = srcq[3];
        unsigned short* gdst = aout + (size_t)(b * Nn + n0 + q) * 1024 + h * 64 + half * 32;
        *(s16x8*)gdst = o0;
        *((s16x8*)gdst + 1) = o1;
        *((s16x8*)gdst + 2) = o2;
        *((s16x8*)gdst + 3) = o3;
    }
}

// ---------------- launch ----------------
extern "C" void kernel_launch(void* const* d_in, const int* in_sizes, int n_in,
                              void* d_out, int out_size, void* d_ws, size_t ws_size,
                              hipStream_t stream) {
    const float* x    = (const float*)d_in[0];
    const float* ctx  = (const float*)d_in[1];
    const float* g1   = (const float*)d_in[2];
    const float* Wq   = (const float*)d_in[3];
    const float* Wkv  = (const float*)d_in[4];
    const float* nkv  = (const float*)d_in[5];
    const float* ctxg = (const float*)d_in[6];
    const float* ctxb = (const float*)d_in[7];
    const float* Wc   = (const float*)d_in[8];
    const float* bc   = (const float*)d_in[9];
    const float* Wout = (const float*)d_in[10];
    const float* g2   = (const float*)d_in[11];
    float* out = (float*)d_out;

    char* w = (char*)d_ws;
    unsigned short* h_    = (unsigned short*)w; w += (size_t)4096 * 1024 * 2;
    unsigned short* ch    = (unsigned short*)w; w += (size_t)512 * 1024 * 2;
    unsigned short* WqkvT = (unsigned short*)w; w += (size_t)1152 * 1024 * 2;
    unsigned short* WcT   = (unsigned short*)w; w += (size_t)128 * 1024 * 2;
    unsigned short* WoutT = (unsigned short*)w; w += (size_t)1024 * 1024 * 2;
    unsigned short* qkv   = (unsigned short*)w; w += (size_t)4096 * QKVN * 2;
    unsigned short* ckv   = (unsigned short*)w; w += (size_t)512 * 128 * 2;
    unsigned short* Kb    = (unsigned short*)w; w += (size_t)Bb * JP * 64 * 2;
    unsigned short* Vt    = (unsigned short*)w; w += (size_t)Bb * 64 * JP * 2;
    unsigned short* aout  = (unsigned short*)w; w += (size_t)4096 * 1024 * 2;

    // fold softmax scale AND log2(e) into Wq so QK^T lands in exp2 domain
    const float qscale = 0.125f * 1.4426950408889634f;

    // weight transposes + input layernorms (one fused launch)
    k_pre<<<6912, 256, 0, stream>>>(Wq, Wkv, Wc, Wout, x, ctx, g1, ctxg, ctxb,
                                    WqkvT, WcT, WoutT, h_, ch, qscale);

    // qkv + ckv projections (m97-style 128x128 GEMM)
    k_gemm_qkv<<<292, 256, 0, stream>>>(h_, WqkvT, qkv, ch, WcT, ckv);

    // build K (row-major) and V^T (coalesced, LDS transpose)
    k_assemble_kv<<<Bb * 38, 256, 0, stream>>>(qkv, ckv, nkv, bc, Kb, Vt);

    // attention: 512 threads = 2 j-teams x 4 waves; 128 q-rows per block; 512 blocks
    k_attn<<<Bb * Hh * (Nn / 128), 512, 0, stream>>>(qkv, Kb, Vt, aout);

    // output projection (128x128 GEMM, bf16 into reused h_) + final LN (bf16 in)
    k_gemm_out<<<256, 256, 0, stream>>>(aout, WoutT, h_);
    k_ln_out<<<4096, 256, 0, stream>>>(h_, g2, out);
}

// Round 17
// 109.778 us; speedup vs baseline: 1.2384x; 1.0380x over previous
//
#include <hip/hip_runtime.h>

typedef __attribute__((ext_vector_type(4)))  float  f32x4;
typedef __attribute__((ext_vector_type(16))) float  f32x16;
typedef __attribute__((ext_vector_type(8)))  short  s16x8;

#define DEVI __device__ __forceinline__

// ---------------- constants ----------------
constexpr int Bb   = 2;
constexpr int Nn   = 2048;
constexpr int Hh   = 16;
constexpr int DHc  = 64;
constexpr int CTXN = 256;
constexpr int Jv   = Nn + 1 + CTXN;   // 2305 valid kv tokens
constexpr int JP   = 2432;            // padded to 38*64 (2 teams x 19 tiles)
constexpr int NPAD = JP - Jv;         // 127 zero-padded tokens (all in team 1)
constexpr int QKVN = Hh*DHc + 2*DHc;  // 1152

// ---------------- helpers ----------------
DEVI unsigned short f2bf(float f) {
    union { float f; unsigned u; } v; v.f = f;
    unsigned r = v.u + 0x7fffu + ((v.u >> 16) & 1u);
    return (unsigned short)(r >> 16);
}
DEVI float bf2f(unsigned short h) {
    union { unsigned u; float f; } v; v.u = ((unsigned)h) << 16;
    return v.f;
}
DEVI unsigned cvt_pk_bf(float lo, float hi) {   // dst.lo=bf16(lo), dst.hi=bf16(hi)
    unsigned r;
    asm("v_cvt_pk_bf16_f32 %0, %1, %2" : "=v"(r) : "v"(lo), "v"(hi));
    return r;
}
DEVI float exp2v(float x) {                      // v_exp_f32 = 2^x
    float r;
    asm("v_exp_f32 %0, %1" : "=v"(r) : "v"(x));
    return r;
}
// async global->LDS, 16B per lane; LDS dest = uniform base + lane*16 (linear)
DEVI void gl_lds16(const void* g, void* l) {
    __builtin_amdgcn_global_load_lds(
        (__attribute__((address_space(1))) void*)g,
        (__attribute__((address_space(3))) void*)l,
        16, 0, 0);
}

// ---------------- fused: weight transposes (blocks 0..2303) + input LNs (2304..6911) -----
__global__ __launch_bounds__(256) void k_pre(const float* __restrict__ Wq,
                                             const float* __restrict__ Wkv,
                                             const float* __restrict__ Wc,
                                             const float* __restrict__ Wout,
                                             const float* __restrict__ x,
                                             const float* __restrict__ ctx,
                                             const float* __restrict__ g1,
                                             const float* __restrict__ cg,
                                             const float* __restrict__ cb,
                                             unsigned short* __restrict__ WqkvT,
                                             unsigned short* __restrict__ WcT,
                                             unsigned short* __restrict__ WoutT,
                                             unsigned short* __restrict__ h,
                                             unsigned short* __restrict__ ch,
                                             float qscale) {
    int bxg = blockIdx.x;
    if (bxg < 2304) {
        __shared__ float tile[32][33];
        int bx = bxg % 72, by = bxg / 72;
        const float* in; unsigned short* out; int C; float scale; int cb_;
        if (bx < 32)      { in = Wq;   out = WqkvT;               C = 1024; scale = qscale; cb_ = bx; }
        else if (bx < 36) { in = Wkv;  out = WqkvT + 1024 * 1024; C = 128;  scale = 1.0f;  cb_ = bx - 32; }
        else if (bx < 40) { in = Wc;   out = WcT;                 C = 128;  scale = 1.0f;  cb_ = bx - 36; }
        else              { in = Wout; out = WoutT;               C = 1024; scale = 1.0f;  cb_ = bx - 40; }
        int tx = threadIdx.x & 31, ty = threadIdx.x >> 5;   // 32 x 8
        int r0 = by * 32, c0 = cb_ * 32;
#pragma unroll
        for (int i = 0; i < 32; i += 8)
            tile[ty + i][tx] = in[(size_t)(r0 + ty + i) * C + c0 + tx];
        __syncthreads();
#pragma unroll
        for (int i = 0; i < 32; i += 8)
            out[(size_t)(c0 + ty + i) * 1024 + r0 + tx] = f2bf(tile[tx][ty + i] * scale);
    } else {
        int row = bxg - 2304, tid = threadIdx.x;
        bool isx = row < 4096;
        const float* rp = isx ? x + (size_t)row * 1024 : ctx + (size_t)(row - 4096) * 1024;
        const float* g  = isx ? g1 : cg;
        float eps = isx ? 1e-5f : 1e-6f;
        unsigned short* o = isx ? h + (size_t)row * 1024 : ch + (size_t)(row - 4096) * 1024;

        f32x4 v = *(const f32x4*)(rp + tid * 4);
        float s = v.x + v.y + v.z + v.w;
        float q = v.x * v.x + v.y * v.y + v.z * v.z + v.w * v.w;
#pragma unroll
        for (int m = 32; m; m >>= 1) { s += __shfl_down(s, m, 64); q += __shfl_down(q, m, 64); }
        __shared__ float ss[4], sq[4];
        int wid = tid >> 6, lane = tid & 63;
        if (lane == 0) { ss[wid] = s; sq[wid] = q; }
        __syncthreads();
        s = ss[0] + ss[1] + ss[2] + ss[3];
        q = sq[0] + sq[1] + sq[2] + sq[3];
        float mean = s * (1.0f / 1024.0f);
        float var  = q * (1.0f / 1024.0f) - mean * mean;
        float rstd = rsqrtf(var + eps);
        f32x4 gg = *(const f32x4*)(g + tid * 4);
        f32x4 r;
#pragma unroll
        for (int e = 0; e < 4; e++) r[e] = (v[e] - mean) * rstd * gg[e];
        if (!isx) {
            f32x4 bb = *(const f32x4*)(cb + tid * 4);
#pragma unroll
            for (int e = 0; e < 4; e++) r[e] += bb[e];
        }
        uint2 ov = make_uint2(cvt_pk_bf(r[0], r[1]), cvt_pk_bf(r[2], r[3]));
        *(uint2*)(o + tid * 4) = ov;
    }
}

// ---------------- final LayerNorm (bf16 in, f32 out) ----------------
__global__ __launch_bounds__(256) void k_ln_out(const unsigned short* __restrict__ in,
                                                const float* __restrict__ g,
                                                float* __restrict__ out) {
    int row = blockIdx.x, tid = threadIdx.x;
    const unsigned short* rp = in + (size_t)row * 1024;
    uint2 raw = *(const uint2*)(rp + tid * 4);
    f32x4 v;
    v.x = bf2f((unsigned short)(raw.x & 0xffff));
    v.y = bf2f((unsigned short)(raw.x >> 16));
    v.z = bf2f((unsigned short)(raw.y & 0xffff));
    v.w = bf2f((unsigned short)(raw.y >> 16));
    float s = v.x + v.y + v.z + v.w;
    float q = v.x * v.x + v.y * v.y + v.z * v.z + v.w * v.w;
#pragma unroll
    for (int m = 32; m; m >>= 1) { s += __shfl_down(s, m, 64); q += __shfl_down(q, m, 64); }
    __shared__ float ss[4], sq[4];
    int wid = tid >> 6, lane = tid & 63;
    if (lane == 0) { ss[wid] = s; sq[wid] = q; }
    __syncthreads();
    s = ss[0] + ss[1] + ss[2] + ss[3];
    q = sq[0] + sq[1] + sq[2] + sq[3];
    float mean = s * (1.0f / 1024.0f);
    float var  = q * (1.0f / 1024.0f) - mean * mean;
    float rstd = rsqrtf(var + 1e-5f);
    f32x4 gg = *(const f32x4*)(g + tid * 4);
    f32x4 r;
#pragma unroll
    for (int e = 0; e < 4; e++) r[e] = (v[e] - mean) * rstd * gg[e];
    *(f32x4*)(out + (size_t)row * 1024 + tid * 4) = r;
}

// ---------------- GEMM core: m97-style 128x128 tile, BK=64, single-buffered -------------
template<int OUT_BF16>
DEVI void gemm128(unsigned short* Al, unsigned short* Bl,
                  const unsigned short* __restrict__ A,
                  const unsigned short* __restrict__ BT,
                  void* __restrict__ C,
                  int M, int N, int K, int bn, int bm) {
    int tid = threadIdx.x;
    int wid = tid >> 6, lane = tid & 63;
    int wm = wid >> 1, wn = wid & 1;
    int lr = lane & 15, lg = lane >> 4;
    int r8 = lane >> 3;
    int sl = (lane & 7) ^ r8;           // pre-swizzled source slot (both-sides XOR, rule #21)

    const unsigned short* Ag = A  + (size_t)(bm * 128 + wid * 32 + r8) * K + sl * 8;
    const unsigned short* Bg = BT + (size_t)(bn * 128 + wid * 32 + r8) * K + sl * 8;

    f32x4 acc[4][4] = {};
    int nk = K >> 6;
#pragma unroll 1
    for (int s = 0; s < nk; ++s) {
        int k0 = s << 6;
        __syncthreads();                 // prev-iter LDS reads done
#pragma unroll
        for (int i = 0; i < 4; i++) {
            gl_lds16(Ag + (size_t)i * 8 * K + k0, Al + wid * 2048 + i * 512);
            gl_lds16(Bg + (size_t)i * 8 * K + k0, Bl + wid * 2048 + i * 512);
        }
        __syncthreads();                 // drains vmcnt; staged data visible
#pragma unroll
        for (int kk = 0; kk < 2; kk++) {
            int co = ((kk * 4 + lg) ^ (lr & 7)) * 8;
            s16x8 af[4], bf[4];
#pragma unroll
            for (int mi = 0; mi < 4; mi++)
                af[mi] = *(const s16x8*)&Al[(wm * 64 + mi * 16 + lr) * 64 + co];
#pragma unroll
            for (int ni = 0; ni < 4; ni++)
                bf[ni] = *(const s16x8*)&Bl[(wn * 64 + ni * 16 + lr) * 64 + co];
#pragma unroll
            for (int mi = 0; mi < 4; mi++)
#pragma unroll
                for (int ni = 0; ni < 4; ni++)
                    acc[mi][ni] = __builtin_amdgcn_mfma_f32_16x16x32_bf16(af[mi], bf[ni], acc[mi][ni], 0, 0, 0);
        }
    }
#pragma unroll
    for (int mi = 0; mi < 4; mi++)
#pragma unroll
        for (int r = 0; r < 4; r++) {
            int row = bm * 128 + wm * 64 + mi * 16 + lg * 4 + r;
#pragma unroll
            for (int ni = 0; ni < 4; ni++) {
                int col = bn * 128 + wn * 64 + ni * 16 + lr;
                float val = acc[mi][ni][r];
                if (OUT_BF16)
                    ((unsigned short*)C)[(size_t)row * N + col] = f2bf(val);
                else
                    ((float*)C)[(size_t)row * N + col] = val;
            }
        }
}

// fused qkv (288 blocks: XCD-chunked 32x9) + ckv (blocks 288..291)
// XCD swizzle (T1, bijective since 288 = 8*36): logical = (g%8)*36 + g/8.
// Each XCD owns 4 consecutive bm groups -> each A-panel fetched by exactly one XCD L2.
__global__ __launch_bounds__(256) void k_gemm_qkv(const unsigned short* __restrict__ h,
                                                  const unsigned short* __restrict__ WqkvT,
                                                  unsigned short* __restrict__ qkv,
                                                  const unsigned short* __restrict__ ch,
                                                  const unsigned short* __restrict__ WcT,
                                                  unsigned short* __restrict__ ckv) {
    __shared__ unsigned short SA[128 * 64];
    __shared__ unsigned short SB[128 * 64];
    int g = blockIdx.x;
    if (g < 288) {
        int id = (g & 7) * 36 + (g >> 3);
        gemm128<1>(SA, SB, h, WqkvT, qkv, 4096, 1152, 1024, id % 9, id / 9);
    } else {
        gemm128<1>(SA, SB, ch, WcT, ckv, 512, 128, 1024, 0, g - 288);
    }
}

// out projection -> bf16 into reused h_ buffer; XCD-chunked (256 = 8*32)
__global__ __launch_bounds__(256) void k_gemm_out(const unsigned short* __restrict__ aout,
                                                  const unsigned short* __restrict__ WoutT,
                                                  unsigned short* __restrict__ preout) {
    __shared__ unsigned short SA[128 * 64];
    __shared__ unsigned short SB[128 * 64];
    int g = blockIdx.x;
    int id = (g & 7) * 32 + (g >> 3);
    gemm128<1>(SA, SB, aout, WoutT, preout, 4096, 1024, 1024, id % 8, id / 8);
}

// ---------------- assemble K (row-major) and V^T via LDS transpose, coalesced ------------
__global__ __launch_bounds__(256) void k_assemble_kv(const unsigned short* __restrict__ qkv,
                                                     const unsigned short* __restrict__ ckv,
                                                     const float* __restrict__ nkv,
                                                     const float* __restrict__ bc,
                                                     unsigned short* __restrict__ Kb,
                                                     unsigned short* __restrict__ Vt) {
    __shared__ unsigned short Vl[64][66];
    int bid = blockIdx.x;
    int b = bid / 38, jt = bid % 38;
    int j0 = jt * 64;
    int tid = threadIdx.x;
    int jl = tid >> 2, qu = tid & 3;     // 64 rows x 4 quarters (16 shorts each)
    int j = j0 + jl;

    unsigned short kbuf[16], vbuf[16];
    if (j < Nn) {
        const unsigned short* r = qkv + (size_t)(b * Nn + j) * QKVN + Hh * DHc;
        *(s16x8*)&kbuf[0] = *(const s16x8*)(r + qu * 16);
        *(s16x8*)&kbuf[8] = *(const s16x8*)(r + qu * 16 + 8);
        *(s16x8*)&vbuf[0] = *(const s16x8*)(r + 64 + qu * 16);
        *(s16x8*)&vbuf[8] = *(const s16x8*)(r + 64 + qu * 16 + 8);
    } else if (j == Nn) {
#pragma unroll
        for (int i = 0; i < 16; i++) {
            kbuf[i] = f2bf(nkv[qu * 16 + i]);
            vbuf[i] = f2bf(nkv[64 + qu * 16 + i]);
        }
    } else if (j < Jv) {
        const unsigned short* r = ckv + (size_t)(b * CTXN + (j - Nn - 1)) * 128;
#pragma unroll
        for (int i = 0; i < 16; i++) {
            kbuf[i] = f2bf(bf2f(r[qu * 16 + i]) + bc[qu * 16 + i]);
            vbuf[i] = f2bf(bf2f(r[64 + qu * 16 + i]) + bc[64 + qu * 16 + i]);
        }
    } else {
#pragma unroll
        for (int i = 0; i < 16; i++) { kbuf[i] = 0; vbuf[i] = 0; }
    }
    // K: direct coalesced store
    *(s16x8*)(Kb + ((size_t)b * JP + j) * 64 + qu * 16)     = *(s16x8*)&kbuf[0];
    *(s16x8*)(Kb + ((size_t)b * JP + j) * 64 + qu * 16 + 8) = *(s16x8*)&kbuf[8];
    // V: stage row-major into LDS
#pragma unroll
    for (int i = 0; i < 16; i++) Vl[jl][qu * 16 + i] = vbuf[i];
    __syncthreads();
    // transpose out: thread -> (d = it*32 + tid>>3, 16B chunk pt = tid&7 of the 64-j row)
#pragma unroll
    for (int it = 0; it < 2; it++) {
        int d = it * 32 + (tid >> 3), pt = tid & 7;
        unsigned short ob[8];
#pragma unroll
        for (int i = 0; i < 8; i++) ob[i] = Vl[pt * 8 + i][d];
        *(s16x8*)(Vt + ((size_t)b * 64 + d) * JP + j0 + pt * 8) = *(s16x8*)&ob[0];
    }
}

// ---------------- flash attention: j-split teams, 32x32 MFMA, in-register P ----------------
// grid: b(2) x h(16) x qtile(16).  block = 512 = 8 waves = 2 j-teams x 4 waves.
// No max subtraction (scores bounded; softmax shift-invariant): p = exp2(s) raw.
// No pad masking: padded K/V rows are exactly zero -> each contributes exactly 1 to L
// (exp2(0)) and 0 to O; team 1 subtracts the exact count NPAD=127 from its L.
__global__ __launch_bounds__(512) void k_attn(const unsigned short* __restrict__ qkv,
                                              const unsigned short* __restrict__ Kb,
                                              const unsigned short* __restrict__ Vt,
                                              unsigned short* __restrict__ aout) {
    __shared__ unsigned short KV[2][2][2][64 * 64];  // [team][buf][0=K j-rows|1=V^T d-rows] : 64 KB

    int bid = blockIdx.x;
    int qt = bid & 15, h = (bid >> 4) & 15, b = bid >> 8;
    int tid = threadIdx.x, wid = tid >> 6, lane = tid & 63;
    int tm = wid >> 2, tw = wid & 3;
    int l31 = lane & 31, hi = lane >> 5;
    int n0 = qt * 128 + tw * 32;
    int r8 = lane >> 3;
    int sl = (lane & 7) ^ r8;
    int x7 = l31 & 7;
    int jb = tm * 1216;                              // team j-base (19 tiles of 64)

    // Q B-frags: col q = n0+l31, k(d) = kk*16 + hi*8 + e
    s16x8 qf[4];
#pragma unroll
    for (int kk = 0; kk < 4; kk++)
        qf[kk] = *(const s16x8*)(qkv + (size_t)(b * Nn + n0 + l31) * QKVN + h * 64 + kk * 16 + hi * 8);

    f32x16 O0 = {}, O1 = {};            // O^T: col q=l31; d = df*32 + (r&3)+8*(r>>2)+4*hi
    float Lv = 0.0f;

    const unsigned short* Kg = Kb + ((size_t)b * JP + jb + tw * 16 + r8) * 64 + sl * 8;
    const unsigned short* Vg = Vt + ((size_t)b * 64 + tw * 16 + r8) * JP + jb + sl * 8;

    auto stage = [&](int t, int buf) {
#pragma unroll
        for (int i = 0; i < 2; i++) {
            gl_lds16(Kg + ((size_t)t * 64 + i * 8) * 64, &KV[tm][buf][0][tw * 1024 + i * 512]);
            gl_lds16(Vg + (size_t)i * 8 * JP + t * 64,   &KV[tm][buf][1][tw * 1024 + i * 512]);
        }
    };

    auto build_pf = [&](const f32x16& s, int w) -> s16x8 {
        unsigned c0 = cvt_pk_bf(s[8 * w + 0], s[8 * w + 1]);
        unsigned c1 = cvt_pk_bf(s[8 * w + 2], s[8 * w + 3]);
        unsigned c2 = cvt_pk_bf(s[8 * w + 4], s[8 * w + 5]);
        unsigned c3 = cvt_pk_bf(s[8 * w + 6], s[8 * w + 7]);
        asm("v_permlane32_swap_b32 %0, %1" : "+v"(c0), "+v"(c2));
        asm("v_permlane32_swap_b32 %0, %1" : "+v"(c1), "+v"(c3));
        union { unsigned u[4]; s16x8 v; } pu;
        pu.u[0] = c0; pu.u[1] = c1; pu.u[2] = c2; pu.u[3] = c3;
        return pu.v;
    };

    stage(0, 0);
    asm volatile("s_waitcnt vmcnt(0)" ::: "memory");
    asm volatile("s_barrier" ::: "memory");
    int cur = 0;
#pragma unroll 1
    for (int t = 0; t < 19; ++t) {
        if (t < 18) {
            stage(t + 1, cur ^ 1);                          // 4 loads into other buf
            asm volatile("s_waitcnt vmcnt(4)" ::: "memory"); // my stage(t) landed; t+1 in flight
        } else {
            asm volatile("s_waitcnt vmcnt(0)" ::: "memory");
        }
        asm volatile("s_barrier" ::: "memory");              // all waves' stage(t) landed
        __builtin_amdgcn_sched_barrier(0);
        const unsigned short* Kl = &KV[tm][cur][0][0];
        const unsigned short* Vl = &KV[tm][cur][1][0];

        // S^T = K Q^T : lane = col q; rows j = jb + t*64 + jf*32 + (r&3)+8*(r>>2)+4*hi
        f32x16 s0 = {}, s1 = {};
        __builtin_amdgcn_s_setprio(1);
#pragma unroll
        for (int kk = 0; kk < 4; kk++) {
            int co = ((kk * 2 + hi) ^ x7) * 8;
            s16x8 k0 = *(const s16x8*)&Kl[l31 * 64 + co];
            s16x8 k1 = *(const s16x8*)&Kl[(32 + l31) * 64 + co];
            s0 = __builtin_amdgcn_mfma_f32_32x32x16_bf16(k0, qf[kk], s0, 0, 0, 0);
            s1 = __builtin_amdgcn_mfma_f32_32x32x16_bf16(k1, qf[kk], s1, 0, 0, 0);
        }
        __builtin_amdgcn_s_setprio(0);

        // softmax weights: p = exp2(s); padded rows give exactly 1 (corrected at end)
        float sum = 0.0f;
#pragma unroll
        for (int r = 0; r < 16; r++) { s0[r] = exp2v(s0[r]); sum += s0[r]; }
#pragma unroll
        for (int r = 0; r < 16; r++) { s1[r] = exp2v(s1[r]); sum += s1[r]; }
        Lv += sum;

        // O^T += V^T P^T ; P^T frags in-register (padded V rows are zero -> no O effect)
        __builtin_amdgcn_s_setprio(1);
#pragma unroll
        for (int ks = 0; ks < 4; ks++) {
            s16x8 pf = (ks < 2) ? build_pf(s0, ks & 1) : build_pf(s1, ks & 1);
            int co = ((ks * 2 + hi) ^ x7) * 8;
            s16x8 v0 = *(const s16x8*)&Vl[l31 * 64 + co];
            s16x8 v1 = *(const s16x8*)&Vl[(32 + l31) * 64 + co];
            O0 = __builtin_amdgcn_mfma_f32_32x32x16_bf16(v0, pf, O0, 0, 0, 0);
            O1 = __builtin_amdgcn_mfma_f32_32x32x16_bf16(v1, pf, O1, 0, 0, 0);
        }
        __builtin_amdgcn_s_setprio(0);
        __builtin_amdgcn_sched_barrier(0);
        asm volatile("s_barrier" ::: "memory");  // all waves done reading buf cur
        cur ^= 1;
    }

    // combine partner-lane L (other 32 j's of same q within team)
    Lv += __shfl_xor(Lv, 32, 64);
    if (tm == 1) Lv -= (float)NPAD;      // exact: 127 padded tokens contributed exp2(0)=1 each

    // ------- team merge via LDS (KV dead now): plain adds -------
    float* Ob = (float*)&KV[0][0][0][0];                 // [4][64][33] f32 (+1 pad)
    float* Ml = Ob + 4 * 64 * 33;                        // [4][64] L values
    unsigned short* slabs = (unsigned short*)(Ml + 4 * 64); // team0: 4 x (32q x 72)

    __syncthreads();
    if (tm == 1) {
        float* dst = Ob + ((size_t)tw * 64 + lane) * 33;
#pragma unroll
        for (int r = 0; r < 16; r++) { dst[r] = O0[r]; dst[16 + r] = O1[r]; }
        Ml[tw * 64 + lane] = Lv;
    }
    __syncthreads();
    if (tm == 0) {
        const float* src = Ob + ((size_t)tw * 64 + lane) * 33;
        float rl = 1.0f / (Lv + Ml[tw * 64 + lane]);

        unsigned short* slab = slabs + tw * 2304;        // 32 q x 72
#pragma unroll
        for (int rq = 0; rq < 4; rq++) {
            uint2 w0 = make_uint2(
                cvt_pk_bf((O0[rq * 4 + 0] + src[rq * 4 + 0]) * rl,
                          (O0[rq * 4 + 1] + src[rq * 4 + 1]) * rl),
                cvt_pk_bf((O0[rq * 4 + 2] + src[rq * 4 + 2]) * rl,
                          (O0[rq * 4 + 3] + src[rq * 4 + 3]) * rl));
            *(uint2*)&slab[l31 * 72 + rq * 8 + hi * 4] = w0;
            uint2 w1 = make_uint2(
                cvt_pk_bf((O1[rq * 4 + 0] + src[16 + rq * 4 + 0]) * rl,
                          (O1[rq * 4 + 1] + src[16 + rq * 4 + 1]) * rl),
                cvt_pk_bf((O1[rq * 4 + 2] + src[16 + rq * 4 + 2]) * rl,
                          (O1[rq * 4 + 3] + src[16 + rq * 4 + 3]) * rl));
            *(uint2*)&slab[l31 * 72 + 32 + rq * 8 + hi * 4] = w1;
        }
        // each lane stores 32 shorts
        int q = lane >> 1, half = lane & 1;
        const s16x8* srcq = (const s16x8*)&slab[q * 72 + half * 32];
        s16x8 o0 = srcq[0], o1 = srcq[1], o2 = srcq[2], o3 = srcq[3];
        unsigned short* gdst = aout + (size_t)(b * Nn + n0 + q) * 1024 + h * 64 + half * 32;
        *(s16x8*)gdst = o0;
        *((s16x8*)gdst + 1) = o1;
        *((s16x8*)gdst + 2) = o2;
        *((s16x8*)gdst + 3) = o3;
    }
}

// ---------------- launch ----------------
extern "C" void kernel_launch(void* const* d_in, const int* in_sizes, int n_in,
                              void* d_out, int out_size, void* d_ws, size_t ws_size,
                              hipStream_t stream) {
    const float* x    = (const float*)d_in[0];
    const float* ctx  = (const float*)d_in[1];
    const float* g1   = (const float*)d_in[2];
    const float* Wq   = (const float*)d_in[3];
    const float* Wkv  = (const float*)d_in[4];
    const float* nkv  = (const float*)d_in[5];
    const float* ctxg = (const float*)d_in[6];
    const float* ctxb = (const float*)d_in[7];
    const float* Wc   = (const float*)d_in[8];
    const float* bc   = (const float*)d_in[9];
    const float* Wout = (const float*)d_in[10];
    const float* g2   = (const float*)d_in[11];
    float* out = (float*)d_out;

    char* w = (char*)d_ws;
    unsigned short* h_    = (unsigned short*)w; w += (size_t)4096 * 1024 * 2;
    unsigned short* ch    = (unsigned short*)w; w += (size_t)512 * 1024 * 2;
    unsigned short* WqkvT = (unsigned short*)w; w += (size_t)1152 * 1024 * 2;
    unsigned short* WcT   = (unsigned short*)w; w += (size_t)128 * 1024 * 2;
    unsigned short* WoutT = (unsigned short*)w; w += (size_t)1024 * 1024 * 2;
    unsigned short* qkv   = (unsigned short*)w; w += (size_t)4096 * QKVN * 2;
    unsigned short* ckv   = (unsigned short*)w; w += (size_t)512 * 128 * 2;
    unsigned short* Kb    = (unsigned short*)w; w += (size_t)Bb * JP * 64 * 2;
    unsigned short* Vt    = (unsigned short*)w; w += (size_t)Bb * 64 * JP * 2;
    unsigned short* aout  = (unsigned short*)w; w += (size_t)4096 * 1024 * 2;

    // fold softmax scale AND log2(e) into Wq so QK^T lands in exp2 domain
    const float qscale = 0.125f * 1.4426950408889634f;

    // weight transposes + input layernorms (one fused launch)
    k_pre<<<6912, 256, 0, stream>>>(Wq, Wkv, Wc, Wout, x, ctx, g1, ctxg, ctxb,
                                    WqkvT, WcT, WoutT, h_, ch, qscale);

    // qkv + ckv projections (128x128 GEMM, XCD-chunked)
    k_gemm_qkv<<<292, 256, 0, stream>>>(h_, WqkvT, qkv, ch, WcT, ckv);

    // build K (row-major) and V^T (coalesced, LDS transpose)
    k_assemble_kv<<<Bb * 38, 256, 0, stream>>>(qkv, ckv, nkv, bc, Kb, Vt);

    // attention: 512 threads = 2 j-teams x 4 waves; 128 q-rows per block; 512 blocks
    k_attn<<<Bb * Hh * (Nn / 128), 512, 0, stream>>>(qkv, Kb, Vt, aout);

    // output projection (128x128 GEMM, XCD-chunked, bf16 into reused h_) + final LN
    k_gemm_out<<<256, 256, 0, stream>>>(aout, WoutT, h_);
    k_ln_out<<<4096, 256, 0, stream>>>(h_, g2, out);
}

// Round 18
// 105.347 us; speedup vs baseline: 1.2905x; 1.0421x over previous
//
#include <hip/hip_runtime.h>

typedef __attribute__((ext_vector_type(4)))  float  f32x4;
typedef __attribute__((ext_vector_type(16))) float  f32x16;
typedef __attribute__((ext_vector_type(8)))  short  s16x8;

#define DEVI __device__ __forceinline__

// ---------------- constants ----------------
constexpr int Bb   = 2;
constexpr int Nn   = 2048;
constexpr int Hh   = 16;
constexpr int DHc  = 64;
constexpr int CTXN = 256;
constexpr int Jv   = Nn + 1 + CTXN;   // 2305 valid kv tokens
constexpr int JP   = 2432;            // padded to 38*64 (2 teams x 19 tiles)
constexpr int NPAD = JP - Jv;         // 127 zero-padded tokens (all in team 1)
constexpr int QKVN = Hh*DHc + 2*DHc;  // 1152

// ---------------- helpers ----------------
DEVI unsigned short f2bf(float f) {
    union { float f; unsigned u; } v; v.f = f;
    unsigned r = v.u + 0x7fffu + ((v.u >> 16) & 1u);
    return (unsigned short)(r >> 16);
}
DEVI float bf2f(unsigned short h) {
    union { unsigned u; float f; } v; v.u = ((unsigned)h) << 16;
    return v.f;
}
DEVI unsigned cvt_pk_bf(float lo, float hi) {   // dst.lo=bf16(lo), dst.hi=bf16(hi)
    unsigned r;
    asm("v_cvt_pk_bf16_f32 %0, %1, %2" : "=v"(r) : "v"(lo), "v"(hi));
    return r;
}
DEVI float exp2v(float x) {                      // v_exp_f32 = 2^x
    float r;
    asm("v_exp_f32 %0, %1" : "=v"(r) : "v"(x));
    return r;
}
// async global->LDS, 16B per lane; LDS dest = uniform base + lane*16 (linear)
DEVI void gl_lds16(const void* g, void* l) {
    __builtin_amdgcn_global_load_lds(
        (__attribute__((address_space(1))) void*)g,
        (__attribute__((address_space(3))) void*)l,
        16, 0, 0);
}

// ---------------- fused: weight transposes (blocks 0..2303) + input LNs (2304..6911) -----
__global__ __launch_bounds__(256) void k_pre(const float* __restrict__ Wq,
                                             const float* __restrict__ Wkv,
                                             const float* __restrict__ Wc,
                                             const float* __restrict__ Wout,
                                             const float* __restrict__ x,
                                             const float* __restrict__ ctx,
                                             const float* __restrict__ g1,
                                             const float* __restrict__ cg,
                                             const float* __restrict__ cb,
                                             unsigned short* __restrict__ WqkvT,
                                             unsigned short* __restrict__ WcT,
                                             unsigned short* __restrict__ WoutT,
                                             unsigned short* __restrict__ h,
                                             unsigned short* __restrict__ ch,
                                             float qscale) {
    int bxg = blockIdx.x;
    if (bxg < 2304) {
        __shared__ float tile[32][33];
        int bx = bxg % 72, by = bxg / 72;
        const float* in; unsigned short* out; int C; float scale; int cb_;
        if (bx < 32)      { in = Wq;   out = WqkvT;               C = 1024; scale = qscale; cb_ = bx; }
        else if (bx < 36) { in = Wkv;  out = WqkvT + 1024 * 1024; C = 128;  scale = 1.0f;  cb_ = bx - 32; }
        else if (bx < 40) { in = Wc;   out = WcT;                 C = 128;  scale = 1.0f;  cb_ = bx - 36; }
        else              { in = Wout; out = WoutT;               C = 1024; scale = 1.0f;  cb_ = bx - 40; }
        int tx = threadIdx.x & 31, ty = threadIdx.x >> 5;   // 32 x 8
        int r0 = by * 32, c0 = cb_ * 32;
#pragma unroll
        for (int i = 0; i < 32; i += 8)
            tile[ty + i][tx] = in[(size_t)(r0 + ty + i) * C + c0 + tx];
        __syncthreads();
#pragma unroll
        for (int i = 0; i < 32; i += 8)
            out[(size_t)(c0 + ty + i) * 1024 + r0 + tx] = f2bf(tile[tx][ty + i] * scale);
    } else {
        int row = bxg - 2304, tid = threadIdx.x;
        bool isx = row < 4096;
        const float* rp = isx ? x + (size_t)row * 1024 : ctx + (size_t)(row - 4096) * 1024;
        const float* g  = isx ? g1 : cg;
        float eps = isx ? 1e-5f : 1e-6f;
        unsigned short* o = isx ? h + (size_t)row * 1024 : ch + (size_t)(row - 4096) * 1024;

        f32x4 v = *(const f32x4*)(rp + tid * 4);
        float s = v.x + v.y + v.z + v.w;
        float q = v.x * v.x + v.y * v.y + v.z * v.z + v.w * v.w;
#pragma unroll
        for (int m = 32; m; m >>= 1) { s += __shfl_down(s, m, 64); q += __shfl_down(q, m, 64); }
        __shared__ float ss[4], sq[4];
        int wid = tid >> 6, lane = tid & 63;
        if (lane == 0) { ss[wid] = s; sq[wid] = q; }
        __syncthreads();
        s = ss[0] + ss[1] + ss[2] + ss[3];
        q = sq[0] + sq[1] + sq[2] + sq[3];
        float mean = s * (1.0f / 1024.0f);
        float var  = q * (1.0f / 1024.0f) - mean * mean;
        float rstd = rsqrtf(var + eps);
        f32x4 gg = *(const f32x4*)(g + tid * 4);
        f32x4 r;
#pragma unroll
        for (int e = 0; e < 4; e++) r[e] = (v[e] - mean) * rstd * gg[e];
        if (!isx) {
            f32x4 bb = *(const f32x4*)(cb + tid * 4);
#pragma unroll
            for (int e = 0; e < 4; e++) r[e] += bb[e];
        }
        uint2 ov = make_uint2(cvt_pk_bf(r[0], r[1]), cvt_pk_bf(r[2], r[3]));
        *(uint2*)(o + tid * 4) = ov;
    }
}

// ---------------- final LayerNorm (bf16 in, f32 out) ----------------
__global__ __launch_bounds__(256) void k_ln_out(const unsigned short* __restrict__ in,
                                                const float* __restrict__ g,
                                                float* __restrict__ out) {
    int row = blockIdx.x, tid = threadIdx.x;
    const unsigned short* rp = in + (size_t)row * 1024;
    uint2 raw = *(const uint2*)(rp + tid * 4);
    f32x4 v;
    v.x = bf2f((unsigned short)(raw.x & 0xffff));
    v.y = bf2f((unsigned short)(raw.x >> 16));
    v.z = bf2f((unsigned short)(raw.y & 0xffff));
    v.w = bf2f((unsigned short)(raw.y >> 16));
    float s = v.x + v.y + v.z + v.w;
    float q = v.x * v.x + v.y * v.y + v.z * v.z + v.w * v.w;
#pragma unroll
    for (int m = 32; m; m >>= 1) { s += __shfl_down(s, m, 64); q += __shfl_down(q, m, 64); }
    __shared__ float ss[4], sq[4];
    int wid = tid >> 6, lane = tid & 63;
    if (lane == 0) { ss[wid] = s; sq[wid] = q; }
    __syncthreads();
    s = ss[0] + ss[1] + ss[2] + ss[3];
    q = sq[0] + sq[1] + sq[2] + sq[3];
    float mean = s * (1.0f / 1024.0f);
    float var  = q * (1.0f / 1024.0f) - mean * mean;
    float rstd = rsqrtf(var + 1e-5f);
    f32x4 gg = *(const f32x4*)(g + tid * 4);
    f32x4 r;
#pragma unroll
    for (int e = 0; e < 4; e++) r[e] = (v[e] - mean) * rstd * gg[e];
    *(f32x4*)(out + (size_t)row * 1024 + tid * 4) = r;
}

// ------ GEMM core: 128x128 tile, 2-buffer counted-vmcnt ring (T4 at low occupancy) -------
// 4 waves (2x2), wave = 64x64 (4x4 frags): 32 MFMA per K-step vs 16 ds_read_b128.
// 64 KB LDS -> 2 blocks/CU. stage(s+1) stays in flight across the compute barrier:
// per wave 8 loads/stage; vmcnt(8) = stage(s) landed. End barrier protects buf before
// restage (2-buffer safe: stage(s+2) into cur happens after end barrier of step s).
template<int OUT_BF16>
DEVI void gemm128(unsigned short* SAb, unsigned short* SBb,
                  const unsigned short* __restrict__ A,
                  const unsigned short* __restrict__ BT,
                  void* __restrict__ C,
                  int M, int N, int K, int bn, int bm) {
    int tid = threadIdx.x;
    int wid = tid >> 6, lane = tid & 63;
    int wm = wid >> 1, wn = wid & 1;
    int lr = lane & 15, lg = lane >> 4;
    int r8 = lane >> 3;
    int sl = (lane & 7) ^ r8;           // pre-swizzled source slot (both-sides XOR, rule #21)

    const unsigned short* Ag = A  + (size_t)(bm * 128 + wid * 32 + r8) * K + sl * 8;
    const unsigned short* Bg = BT + (size_t)(bn * 128 + wid * 32 + r8) * K + sl * 8;

    auto stage = [&](int buf, int s) {
        int k0 = s << 6;
        unsigned short* SA = SAb + buf * (128 * 64);
        unsigned short* SB = SBb + buf * (128 * 64);
#pragma unroll
        for (int i = 0; i < 4; i++) {
            gl_lds16(Ag + (size_t)i * 8 * K + k0, SA + wid * 2048 + i * 512);
            gl_lds16(Bg + (size_t)i * 8 * K + k0, SB + wid * 2048 + i * 512);
        }
    };

    f32x4 acc[4][4] = {};
    int nk = K >> 6;
    stage(0, 0);
    int cur = 0;
#pragma unroll 1
    for (int s = 0; s < nk; ++s) {
        if (s + 1 < nk) {
            stage(cur ^ 1, s + 1);                           // 8 loads into other buf
            asm volatile("s_waitcnt vmcnt(8)" ::: "memory"); // my stage(s) landed
        } else {
            asm volatile("s_waitcnt vmcnt(0)" ::: "memory");
        }
        __builtin_amdgcn_s_barrier();                        // all waves' stage(s) landed
        __builtin_amdgcn_sched_barrier(0);
        const unsigned short* Al = SAb + cur * (128 * 64);
        const unsigned short* Bl = SBb + cur * (128 * 64);
#pragma unroll
        for (int kk = 0; kk < 2; kk++) {
            int co = ((kk * 4 + lg) ^ (lr & 7)) * 8;
            s16x8 af[4], bf[4];
#pragma unroll
            for (int mi = 0; mi < 4; mi++)
                af[mi] = *(const s16x8*)&Al[(wm * 64 + mi * 16 + lr) * 64 + co];
#pragma unroll
            for (int ni = 0; ni < 4; ni++)
                bf[ni] = *(const s16x8*)&Bl[(wn * 64 + ni * 16 + lr) * 64 + co];
#pragma unroll
            for (int mi = 0; mi < 4; mi++)
#pragma unroll
                for (int ni = 0; ni < 4; ni++)
                    acc[mi][ni] = __builtin_amdgcn_mfma_f32_16x16x32_bf16(af[mi], bf[ni], acc[mi][ni], 0, 0, 0);
        }
        __builtin_amdgcn_sched_barrier(0);
        __builtin_amdgcn_s_barrier();            // all waves done reading buf cur
        cur ^= 1;
    }
#pragma unroll
    for (int mi = 0; mi < 4; mi++)
#pragma unroll
        for (int r = 0; r < 4; r++) {
            int row = bm * 128 + wm * 64 + mi * 16 + lg * 4 + r;
#pragma unroll
            for (int ni = 0; ni < 4; ni++) {
                int col = bn * 128 + wn * 64 + ni * 16 + lr;
                float val = acc[mi][ni][r];
                if (OUT_BF16)
                    ((unsigned short*)C)[(size_t)row * N + col] = f2bf(val);
                else
                    ((float*)C)[(size_t)row * N + col] = val;
            }
        }
}

// fused qkv (288 blocks: XCD-chunked 32x9) + ckv (blocks 288..291)
__global__ __launch_bounds__(256) void k_gemm_qkv(const unsigned short* __restrict__ h,
                                                  const unsigned short* __restrict__ WqkvT,
                                                  unsigned short* __restrict__ qkv,
                                                  const unsigned short* __restrict__ ch,
                                                  const unsigned short* __restrict__ WcT,
                                                  unsigned short* __restrict__ ckv) {
    __shared__ unsigned short SA[2][128 * 64];
    __shared__ unsigned short SB[2][128 * 64];
    int g = blockIdx.x;
    if (g < 288) {
        int id = (g & 7) * 36 + (g >> 3);
        gemm128<1>(&SA[0][0], &SB[0][0], h, WqkvT, qkv, 4096, 1152, 1024, id % 9, id / 9);
    } else {
        gemm128<1>(&SA[0][0], &SB[0][0], ch, WcT, ckv, 512, 128, 1024, 0, g - 288);
    }
}

// out projection -> bf16 into reused h_ buffer; XCD-chunked (256 = 8*32)
__global__ __launch_bounds__(256) void k_gemm_out(const unsigned short* __restrict__ aout,
                                                  const unsigned short* __restrict__ WoutT,
                                                  unsigned short* __restrict__ preout) {
    __shared__ unsigned short SA[2][128 * 64];
    __shared__ unsigned short SB[2][128 * 64];
    int g = blockIdx.x;
    int id = (g & 7) * 32 + (g >> 3);
    gemm128<1>(&SA[0][0], &SB[0][0], aout, WoutT, preout, 4096, 1024, 1024, id % 8, id / 8);
}

// ---------------- assemble K (row-major) and V^T via LDS transpose, coalesced ------------
__global__ __launch_bounds__(256) void k_assemble_kv(const unsigned short* __restrict__ qkv,
                                                     const unsigned short* __restrict__ ckv,
                                                     const float* __restrict__ nkv,
                                                     const float* __restrict__ bc,
                                                     unsigned short* __restrict__ Kb,
                                                     unsigned short* __restrict__ Vt) {
    __shared__ unsigned short Vl[64][66];
    int bid = blockIdx.x;
    int b = bid / 38, jt = bid % 38;
    int j0 = jt * 64;
    int tid = threadIdx.x;
    int jl = tid >> 2, qu = tid & 3;     // 64 rows x 4 quarters (16 shorts each)
    int j = j0 + jl;

    unsigned short kbuf[16], vbuf[16];
    if (j < Nn) {
        const unsigned short* r = qkv + (size_t)(b * Nn + j) * QKVN + Hh * DHc;
        *(s16x8*)&kbuf[0] = *(const s16x8*)(r + qu * 16);
        *(s16x8*)&kbuf[8] = *(const s16x8*)(r + qu * 16 + 8);
        *(s16x8*)&vbuf[0] = *(const s16x8*)(r + 64 + qu * 16);
        *(s16x8*)&vbuf[8] = *(const s16x8*)(r + 64 + qu * 16 + 8);
    } else if (j == Nn) {
#pragma unroll
        for (int i = 0; i < 16; i++) {
            kbuf[i] = f2bf(nkv[qu * 16 + i]);
            vbuf[i] = f2bf(nkv[64 + qu * 16 + i]);
        }
    } else if (j < Jv) {
        const unsigned short* r = ckv + (size_t)(b * CTXN + (j - Nn - 1)) * 128;
#pragma unroll
        for (int i = 0; i < 16; i++) {
            kbuf[i] = f2bf(bf2f(r[qu * 16 + i]) + bc[qu * 16 + i]);
            vbuf[i] = f2bf(bf2f(r[64 + qu * 16 + i]) + bc[64 + qu * 16 + i]);
        }
    } else {
#pragma unroll
        for (int i = 0; i < 16; i++) { kbuf[i] = 0; vbuf[i] = 0; }
    }
    // K: direct coalesced store
    *(s16x8*)(Kb + ((size_t)b * JP + j) * 64 + qu * 16)     = *(s16x8*)&kbuf[0];
    *(s16x8*)(Kb + ((size_t)b * JP + j) * 64 + qu * 16 + 8) = *(s16x8*)&kbuf[8];
    // V: stage row-major into LDS
#pragma unroll
    for (int i = 0; i < 16; i++) Vl[jl][qu * 16 + i] = vbuf[i];
    __syncthreads();
    // transpose out: thread -> (d = it*32 + tid>>3, 16B chunk pt = tid&7 of the 64-j row)
#pragma unroll
    for (int it = 0; it < 2; it++) {
        int d = it * 32 + (tid >> 3), pt = tid & 7;
        unsigned short ob[8];
#pragma unroll
        for (int i = 0; i < 8; i++) ob[i] = Vl[pt * 8 + i][d];
        *(s16x8*)(Vt + ((size_t)b * 64 + d) * JP + j0 + pt * 8) = *(s16x8*)&ob[0];
    }
}

// ---------------- flash attention: j-split teams, 32x32 MFMA, in-register P ----------------
// grid: b(2) x h(16) x qtile(16).  block = 512 = 8 waves = 2 j-teams x 4 waves.
// No max subtraction (scores bounded; softmax shift-invariant): p = exp2(s) raw.
// No pad masking: padded K/V rows are exactly zero -> each contributes exactly 1 to L
// (exp2(0)) and 0 to O; team 1 subtracts the exact count NPAD=127 from its L.
__global__ __launch_bounds__(512) void k_attn(const unsigned short* __restrict__ qkv,
                                              const unsigned short* __restrict__ Kb,
                                              const unsigned short* __restrict__ Vt,
                                              unsigned short* __restrict__ aout) {
    __shared__ unsigned short KV[2][2][2][64 * 64];  // [team][buf][0=K j-rows|1=V^T d-rows] : 64 KB

    int bid = blockIdx.x;
    int qt = bid & 15, h = (bid >> 4) & 15, b = bid >> 8;
    int tid = threadIdx.x, wid = tid >> 6, lane = tid & 63;
    int tm = wid >> 2, tw = wid & 3;
    int l31 = lane & 31, hi = lane >> 5;
    int n0 = qt * 128 + tw * 32;
    int r8 = lane >> 3;
    int sl = (lane & 7) ^ r8;
    int x7 = l31 & 7;
    int jb = tm * 1216;                              // team j-base (19 tiles of 64)

    // Q B-frags: col q = n0+l31, k(d) = kk*16 + hi*8 + e
    s16x8 qf[4];
#pragma unroll
    for (int kk = 0; kk < 4; kk++)
        qf[kk] = *(const s16x8*)(qkv + (size_t)(b * Nn + n0 + l31) * QKVN + h * 64 + kk * 16 + hi * 8);

    f32x16 O0 = {}, O1 = {};            // O^T: col q=l31; d = df*32 + (r&3)+8*(r>>2)+4*hi
    float Lv = 0.0f;

    const unsigned short* Kg = Kb + ((size_t)b * JP + jb + tw * 16 + r8) * 64 + sl * 8;
    const unsigned short* Vg = Vt + ((size_t)b * 64 + tw * 16 + r8) * JP + jb + sl * 8;

    auto stage = [&](int t, int buf) {
#pragma unroll
        for (int i = 0; i < 2; i++) {
            gl_lds16(Kg + ((size_t)t * 64 + i * 8) * 64, &KV[tm][buf][0][tw * 1024 + i * 512]);
            gl_lds16(Vg + (size_t)i * 8 * JP + t * 64,   &KV[tm][buf][1][tw * 1024 + i * 512]);
        }
    };

    auto build_pf = [&](const f32x16& s, int w) -> s16x8 {
        unsigned c0 = cvt_pk_bf(s[8 * w + 0], s[8 * w + 1]);
        unsigned c1 = cvt_pk_bf(s[8 * w + 2], s[8 * w + 3]);
        unsigned c2 = cvt_pk_bf(s[8 * w + 4], s[8 * w + 5]);
        unsigned c3 = cvt_pk_bf(s[8 * w + 6], s[8 * w + 7]);
        asm("v_permlane32_swap_b32 %0, %1" : "+v"(c0), "+v"(c2));
        asm("v_permlane32_swap_b32 %0, %1" : "+v"(c1), "+v"(c3));
        union { unsigned u[4]; s16x8 v; } pu;
        pu.u[0] = c0; pu.u[1] = c1; pu.u[2] = c2; pu.u[3] = c3;
        return pu.v;
    };

    stage(0, 0);
    asm volatile("s_waitcnt vmcnt(0)" ::: "memory");
    asm volatile("s_barrier" ::: "memory");
    int cur = 0;
#pragma unroll 1
    for (int t = 0; t < 19; ++t) {
        if (t < 18) {
            stage(t + 1, cur ^ 1);                          // 4 loads into other buf
            asm volatile("s_waitcnt vmcnt(4)" ::: "memory"); // my stage(t) landed; t+1 in flight
        } else {
            asm volatile("s_waitcnt vmcnt(0)" ::: "memory");
        }
        asm volatile("s_barrier" ::: "memory");              // all waves' stage(t) landed
        __builtin_amdgcn_sched_barrier(0);
        const unsigned short* Kl = &KV[tm][cur][0][0];
        const unsigned short* Vl = &KV[tm][cur][1][0];

        // S^T = K Q^T : lane = col q; rows j = jb + t*64 + jf*32 + (r&3)+8*(r>>2)+4*hi
        f32x16 s0 = {}, s1 = {};
        __builtin_amdgcn_s_setprio(1);
#pragma unroll
        for (int kk = 0; kk < 4; kk++) {
            int co = ((kk * 2 + hi) ^ x7) * 8;
            s16x8 k0 = *(const s16x8*)&Kl[l31 * 64 + co];
            s16x8 k1 = *(const s16x8*)&Kl[(32 + l31) * 64 + co];
            s0 = __builtin_amdgcn_mfma_f32_32x32x16_bf16(k0, qf[kk], s0, 0, 0, 0);
            s1 = __builtin_amdgcn_mfma_f32_32x32x16_bf16(k1, qf[kk], s1, 0, 0, 0);
        }
        __builtin_amdgcn_s_setprio(0);

        // softmax weights: p = exp2(s); padded rows give exactly 1 (corrected at end)
        float sum = 0.0f;
#pragma unroll
        for (int r = 0; r < 16; r++) { s0[r] = exp2v(s0[r]); sum += s0[r]; }
#pragma unroll
        for (int r = 0; r < 16; r++) { s1[r] = exp2v(s1[r]); sum += s1[r]; }
        Lv += sum;

        // O^T += V^T P^T ; P^T frags in-register (padded V rows are zero -> no O effect)
        __builtin_amdgcn_s_setprio(1);
#pragma unroll
        for (int ks = 0; ks < 4; ks++) {
            s16x8 pf = (ks < 2) ? build_pf(s0, ks & 1) : build_pf(s1, ks & 1);
            int co = ((ks * 2 + hi) ^ x7) * 8;
            s16x8 v0 = *(const s16x8*)&Vl[l31 * 64 + co];
            s16x8 v1 = *(const s16x8*)&Vl[(32 + l31) * 64 + co];
            O0 = __builtin_amdgcn_mfma_f32_32x32x16_bf16(v0, pf, O0, 0, 0, 0);
            O1 = __builtin_amdgcn_mfma_f32_32x32x16_bf16(v1, pf, O1, 0, 0, 0);
        }
        __builtin_amdgcn_s_setprio(0);
        __builtin_amdgcn_sched_barrier(0);
        asm volatile("s_barrier" ::: "memory");  // all waves done reading buf cur
        cur ^= 1;
    }

    // combine partner-lane L (other 32 j's of same q within team)
    Lv += __shfl_xor(Lv, 32, 64);
    if (tm == 1) Lv -= (float)NPAD;      // exact: 127 padded tokens contributed exp2(0)=1 each

    // ------- team merge via LDS (KV dead now): plain adds -------
    float* Ob = (float*)&KV[0][0][0][0];                 // [4][64][33] f32 (+1 pad)
    float* Ml = Ob + 4 * 64 * 33;                        // [4][64] L values
    unsigned short* slabs = (unsigned short*)(Ml + 4 * 64); // team0: 4 x (32q x 72)

    __syncthreads();
    if (tm == 1) {
        float* dst = Ob + ((size_t)tw * 64 + lane) * 33;
#pragma unroll
        for (int r = 0; r < 16; r++) { dst[r] = O0[r]; dst[16 + r] = O1[r]; }
        Ml[tw * 64 + lane] = Lv;
    }
    __syncthreads();
    if (tm == 0) {
        const float* src = Ob + ((size_t)tw * 64 + lane) * 33;
        float rl = 1.0f / (Lv + Ml[tw * 64 + lane]);

        unsigned short* slab = slabs + tw * 2304;        // 32 q x 72
#pragma unroll
        for (int rq = 0; rq < 4; rq++) {
            uint2 w0 = make_uint2(
                cvt_pk_bf((O0[rq * 4 + 0] + src[rq * 4 + 0]) * rl,
                          (O0[rq * 4 + 1] + src[rq * 4 + 1]) * rl),
                cvt_pk_bf((O0[rq * 4 + 2] + src[rq * 4 + 2]) * rl,
                          (O0[rq * 4 + 3] + src[rq * 4 + 3]) * rl));
            *(uint2*)&slab[l31 * 72 + rq * 8 + hi * 4] = w0;
            uint2 w1 = make_uint2(
                cvt_pk_bf((O1[rq * 4 + 0] + src[16 + rq * 4 + 0]) * rl,
                          (O1[rq * 4 + 1] + src[16 + rq * 4 + 1]) * rl),
                cvt_pk_bf((O1[rq * 4 + 2] + src[16 + rq * 4 + 2]) * rl,
                          (O1[rq * 4 + 3] + src[16 + rq * 4 + 3]) * rl));
            *(uint2*)&slab[l31 * 72 + 32 + rq * 8 + hi * 4] = w1;
        }
        // each lane stores 32 shorts
        int q = lane >> 1, half = lane & 1;
        const s16x8* srcq = (const s16x8*)&slab[q * 72 + half * 32];
        s16x8 o0 = srcq[0], o1 = srcq[1], o2 = srcq[2], o3 = srcq[3];
        unsigned short* gdst = aout + (size_t)(b * Nn + n0 + q) * 1024 + h * 64 + half * 32;
        *(s16x8*)gdst = o0;
        *((s16x8*)gdst + 1) = o1;
        *((s16x8*)gdst + 2) = o2;
        *((s16x8*)gdst + 3) = o3;
    }
}

// ---------------- launch ----------------
extern "C" void kernel_launch(void* const* d_in, const int* in_sizes, int n_in,
                              void* d_out, int out_size, void* d_ws, size_t ws_size,
                              hipStream_t stream) {
    const float* x    = (const float*)d_in[0];
    const float* ctx  = (const float*)d_in[1];
    const float* g1   = (const float*)d_in[2];
    const float* Wq   = (const float*)d_in[3];
    const float* Wkv  = (const float*)d_in[4];
    const float* nkv  = (const float*)d_in[5];
    const float* ctxg = (const float*)d_in[6];
    const float* ctxb = (const float*)d_in[7];
    const float* Wc   = (const float*)d_in[8];
    const float* bc   = (const float*)d_in[9];
    const float* Wout = (const float*)d_in[10];
    const float* g2   = (const float*)d_in[11];
    float* out = (float*)d_out;

    char* w = (char*)d_ws;
    unsigned short* h_    = (unsigned short*)w; w += (size_t)4096 * 1024 * 2;
    unsigned short* ch    = (unsigned short*)w; w += (size_t)512 * 1024 * 2;
    unsigned short* WqkvT = (unsigned short*)w; w += (size_t)1152 * 1024 * 2;
    unsigned short* WcT   = (unsigned short*)w; w += (size_t)128 * 1024 * 2;
    unsigned short* WoutT = (unsigned short*)w; w += (size_t)1024 * 1024 * 2;
    unsigned short* qkv   = (unsigned short*)w; w += (size_t)4096 * QKVN * 2;
    unsigned short* ckv   = (unsigned short*)w; w += (size_t)512 * 128 * 2;
    unsigned short* Kb    = (unsigned short*)w; w += (size_t)Bb * JP * 64 * 2;
    unsigned short* Vt    = (unsigned short*)w; w += (size_t)Bb * 64 * JP * 2;
    unsigned short* aout  = (unsigned short*)w; w += (size_t)4096 * 1024 * 2;

    // fold softmax scale AND log2(e) into Wq so QK^T lands in exp2 domain
    const float qscale = 0.125f * 1.4426950408889634f;

    // weight transposes + input layernorms (one fused launch)
    k_pre<<<6912, 256, 0, stream>>>(Wq, Wkv, Wc, Wout, x, ctx, g1, ctxg, ctxb,
                                    WqkvT, WcT, WoutT, h_, ch, qscale);

    // qkv + ckv projections (128x128 dbuf counted-vmcnt GEMM, XCD-chunked)
    k_gemm_qkv<<<292, 256, 0, stream>>>(h_, WqkvT, qkv, ch, WcT, ckv);

    // build K (row-major) and V^T (coalesced, LDS transpose)
    k_assemble_kv<<<Bb * 38, 256, 0, stream>>>(qkv, ckv, nkv, bc, Kb, Vt);

    // attention: 512 threads = 2 j-teams x 4 waves; 128 q-rows per block; 512 blocks
    k_attn<<<Bb * Hh * (Nn / 128), 512, 0, stream>>>(qkv, Kb, Vt, aout);

    // output projection (dbuf GEMM, XCD-chunked, bf16 into reused h_) + final LN
    k_gemm_out<<<256, 256, 0, stream>>>(aout, WoutT, h_);
    k_ln_out<<<4096, 256, 0, stream>>>(h_, g2, out);
}